// Round 17
// baseline (544.809 us; speedup 1.0000x reference)
//
#include <hip/hip_runtime.h>
#include <hip/hip_bf16.h>

// Hierarchical attention, 3 levels. Split-bf16 (hi/lo) MFMA for QKV/scores/PV;
// out-proj commuted with masked mean pool (exact fp32 matvec epilogue).
// r17 = r16 (separate hi/lo u16 planes, perm-free frags) + 2-buffer chunk
// pipeline: chunk kc in buffer kc&1; each phase {load chunk kc+1 -> MFMA kc ->
// ds_write kc+1 -> ONE barrier}. Staging overlaps MFMA; regs phase-transient
// (r12 lesson: never hold chunk sets across barriers). V^T -> XB post-phase-3;
// next head's chunk0 -> XA during phase 3. Barriers ~41 -> ~27.
// LDS 64.3 KB -> 2 blocks/CU; (256,2) no-spill envelope.

typedef short bf16x8 __attribute__((ext_vector_type(8)));
typedef float f32x4 __attribute__((ext_vector_type(4)));
typedef unsigned int u32x4 __attribute__((ext_vector_type(4)));
typedef unsigned short U16;
typedef unsigned int U32;

__device__ __forceinline__ U16 f2bf(float f) {
    __hip_bfloat16 b = __float2bfloat16(f);   // HW cvt (RNE)
    return __builtin_bit_cast(U16, b);
}
__device__ __forceinline__ void split_hl(float f, U16& h, U16& l) {
    h = f2bf(f);
    float hf = __builtin_bit_cast(float, (U32)h << 16);
    l = f2bf(f - hf);
}

#define MFMA(A, B, C) __builtin_amdgcn_mfma_f32_16x16x32_bf16( \
    __builtin_bit_cast(bf16x8, A), __builtin_bit_cast(bf16x8, B), C, 0, 0, 0)

// u16 plane helpers. RS = row stride (u16 units), SW = row swizzle mask.
// Element k of row r lives at 16B-slot ((k>>3) ^ (r & SW)).
template <int RS, int SW>
__device__ __forceinline__ u32x4 fragp(const U16* base, int row, int k, int lhi) {
    int slot = ((k >> 3) + lhi) ^ (row & SW);
    return *(const u32x4*)(base + row * RS + slot * 8);
}
template <int RS, int SW>
__device__ __forceinline__ void put16(U16* base, int row, int col, U16 v) {
    int slot = (col >> 3) ^ (row & SW);
    base[row * RS + slot * 8 + (col & 7)] = v;
}
template <int RS, int SW>
__device__ __forceinline__ void put64(U16* base, int row, int col0,
                                      U16 v0, U16 v1, U16 v2, U16 v3) {
    int slot = (col0 >> 3) ^ (row & SW);
    U32* p = (U32*)(base + row * RS + slot * 8 + (col0 & 7));
    p[0] = (U32)v0 | ((U32)v1 << 16);
    p[1] = (U32)v2 | ((U32)v3 << 16);
}

// stage 8 consecutive elements (cols c8*8..+7) of one row into hi/lo planes
__device__ __forceinline__ void stage8(U16* ph, U16* pl, int row, int c8,
                                       float4 a, float4 b) {
    U16 h[8], l[8];
    split_hl(a.x, h[0], l[0]); split_hl(a.y, h[1], l[1]);
    split_hl(a.z, h[2], l[2]); split_hl(a.w, h[3], l[3]);
    split_hl(b.x, h[4], l[4]); split_hl(b.y, h[5], l[5]);
    split_hl(b.z, h[6], l[6]); split_hl(b.w, h[7], l[7]);
    u32x4 hv, lv;
    #pragma unroll
    for (int q = 0; q < 4; ++q) {
        hv[q] = (U32)h[2*q] | ((U32)h[2*q+1] << 16);
        lv[q] = (U32)l[2*q] | ((U32)l[2*q+1] << 16);
    }
    const int slot = c8 ^ (row & 7);
    *(u32x4*)(ph + row * 64 + slot * 8) = hv;
    *(u32x4*)(pl + row * 64 + slot * 8) = lv;
}

__global__ __launch_bounds__(256) void convert_w(
    const float* __restrict__ Wq, const float* __restrict__ Wo,
    U16* __restrict__ qh, U16* __restrict__ ql,
    U16* __restrict__ oh, U16* __restrict__ ol)
{
    int i = blockIdx.x * 256 + threadIdx.x;
    if (i < 768 * 256) { U16 h, l; split_hl(Wq[i], h, l); qh[i] = h; ql[i] = l; }
    if (i < 256 * 256) { U16 h, l; split_hl(Wo[i], h, l); oh[i] = h; ol[i] = l; }
}

// ---- word level: 1 block = 1 sequence (L=64), 256 threads = 4 waves ----
__global__ __launch_bounds__(256, 2) void word_mfma(
    const float* __restrict__ x, const int* __restrict__ am,
    const U16* __restrict__ Wqh, const U16* __restrict__ Wql,
    const float* __restrict__ bqkv,
    const float* __restrict__ Wo32,   // fp32 [256][256]
    const float* __restrict__ bo,
    U16* __restrict__ sent_hi, U16* __restrict__ sent_lo,
    float* __restrict__ smask)
{
    __shared__ __align__(16) U16 QsH[64 * 64], QsL[64 * 64];  // Q, later P
    __shared__ __align__(16) U16 KsH[64 * 64], KsL[64 * 64];  // K; end: scratch
    __shared__ __align__(16) U16 XAH[64 * 64], XAL[64 * 64];  // chunks 0,2
    __shared__ __align__(16) U16 XBH[64 * 64], XBL[64 * 64];  // chunks 1,3; V^T
    __shared__ float msk[64];
    __shared__ float smsum;

    const int t = threadIdx.x;
    const int w = t >> 6, l = t & 63, l15 = l & 15, lhi = l >> 4;
    const int b = blockIdx.x;
    const float* xb = x + (size_t)b * 16384;

    if (t < 64) msk[t] = (float)am[b * 64 + t];

    const int r0 = t >> 3, c8 = t & 7;
    const int r1 = r0 + 32;

    // prologue: stage chunk 0 into XA (visible at top-of-head barrier)
    {
        float4 s00 = *(const float4*)(xb + r0 * 256 + c8 * 8);
        float4 s01 = *(const float4*)(xb + r0 * 256 + c8 * 8 + 4);
        float4 s10 = *(const float4*)(xb + r1 * 256 + c8 * 8);
        float4 s11 = *(const float4*)(xb + r1 * 256 + c8 * 8 + 4);
        stage8(XAH, XAL, r0, c8, s00, s01);
        stage8(XAH, XAL, r1, c8, s10, s11);
    }

    float po[16];   // pooled-O partials, static-indexed only (uniform h branch)

    #pragma unroll 1
    for (int h = 0; h < 4; ++h) {
        __syncthreads();   // top-of-head: XB (V^T) reads done; staged chunk visible
        f32x4 acc[3][4];
        #pragma unroll
        for (int j = 0; j < 3; ++j)
            #pragma unroll
            for (int mt = 0; mt < 4; ++mt) acc[j][mt] = f32x4{0.f, 0.f, 0.f, 0.f};

        #pragma unroll
        for (int kc = 0; kc < 4; ++kc) {
            const U16* xph = (kc & 1) ? XBH : XAH;   // current chunk planes
            const U16* xpl = (kc & 1) ? XBL : XAL;
            U16* sth = (kc & 1) ? XAH : XBH;         // stage target (kc+1)&1
            U16* stl = (kc & 1) ? XAL : XBL;
            const int ck = ((kc + 1) & 3) * 64;      // kc<3: next chunk; kc==3: chunk0
            const bool doStage = (kc < 3) || (h < 3);
            float4 s00, s01, s10, s11;
            if (doStage) {                            // issue loads early (T14)
                s00 = *(const float4*)(xb + r0 * 256 + ck + c8 * 8);
                s01 = *(const float4*)(xb + r0 * 256 + ck + c8 * 8 + 4);
                s10 = *(const float4*)(xb + r1 * 256 + ck + c8 * 8);
                s11 = *(const float4*)(xb + r1 * 256 + ck + c8 * 8 + 4);
            }
            #pragma unroll
            for (int ks = 0; ks < 2; ++ks) {
                const int kt = ks * 32;              // k within 64-wide tile
                const int kk = kc * 64 + kt + lhi * 8;
                const size_t wr0 = (size_t)(          h * 64 + w * 16 + l15) * 256 + kk;
                const size_t wr1 = (size_t)(256     + h * 64 + w * 16 + l15) * 256 + kk;
                const size_t wr2 = (size_t)(512     + h * 64 + w * 16 + l15) * 256 + kk;
                u32x4 wh0 = *(const u32x4*)(Wqh + wr0);
                u32x4 wl0 = *(const u32x4*)(Wql + wr0);
                u32x4 wh1 = *(const u32x4*)(Wqh + wr1);
                u32x4 wl1 = *(const u32x4*)(Wql + wr1);
                u32x4 wh2 = *(const u32x4*)(Wqh + wr2);
                u32x4 wl2 = *(const u32x4*)(Wql + wr2);
                #pragma unroll
                for (int mt = 0; mt < 4; ++mt) {
                    u32x4 xh = fragp<64, 7>(xph, mt * 16 + l15, kt, lhi);
                    u32x4 xl = fragp<64, 7>(xpl, mt * 16 + l15, kt, lhi);
                    acc[0][mt] = MFMA(xh, wh0, acc[0][mt]);
                    acc[0][mt] = MFMA(xh, wl0, acc[0][mt]);
                    acc[0][mt] = MFMA(xl, wh0, acc[0][mt]);
                    acc[1][mt] = MFMA(xh, wh1, acc[1][mt]);
                    acc[1][mt] = MFMA(xh, wl1, acc[1][mt]);
                    acc[1][mt] = MFMA(xl, wh1, acc[1][mt]);
                    acc[2][mt] = MFMA(xh, wh2, acc[2][mt]);
                    acc[2][mt] = MFMA(xh, wl2, acc[2][mt]);
                    acc[2][mt] = MFMA(xl, wh2, acc[2][mt]);
                }
            }
            if (doStage) {                            // write after MFMA cluster
                stage8(sth, stl, r0, c8, s00, s01);
                stage8(sth, stl, r1, c8, s10, s11);
            }
            __syncthreads();   // end of phase: chunk kc+1 staged, kc reads done
        }
        // ---- write Q / K planes + V^T into XB (chunk-3 reads done) ----
        {
            const float bQ = bqkv[      h * 64 + w * 16 + l15];
            const float bK = bqkv[256 + h * 64 + w * 16 + l15];
            #pragma unroll
            for (int mt = 0; mt < 4; ++mt) {
                #pragma unroll
                for (int r = 0; r < 4; ++r) {
                    U16 vH, vL;
                    split_hl(acc[0][mt][r] + bQ, vH, vL);
                    put16<64, 7>(QsH, mt * 16 + lhi * 4 + r, w * 16 + l15, vH);
                    put16<64, 7>(QsL, mt * 16 + lhi * 4 + r, w * 16 + l15, vL);
                    split_hl(acc[1][mt][r] + bK, vH, vL);
                    put16<64, 7>(KsH, mt * 16 + lhi * 4 + r, w * 16 + l15, vH);
                    put16<64, 7>(KsL, mt * 16 + lhi * 4 + r, w * 16 + l15, vL);
                }
            }
            const float bV = bqkv[512 + h * 64 + w * 16 + l15];
            const int d = w * 16 + l15;
            #pragma unroll
            for (int mt = 0; mt < 4; ++mt) {
                U16 h4[4], l4[4];
                #pragma unroll
                for (int r = 0; r < 4; ++r)
                    split_hl(acc[2][mt][r] + bV, h4[r], l4[r]);
                put64<64, 7>(XBH, d, mt * 16 + lhi * 4, h4[0], h4[1], h4[2], h4[3]);
                put64<64, 7>(XBL, d, mt * 16 + lhi * 4, l4[0], l4[1], l4[2], l4[3]);
            }
        }
        __syncthreads();   // Q, K, V^T ready
        if (h == 0 && t == 0) {
            float s = 0.f;
            for (int i = 0; i < 64; ++i) s += msk[i];
            smsum = s;
        }

        // ------- scores + softmax + P (wave w owns row-tile w) -------
        {
            f32x4 sa[4];
            #pragma unroll
            for (int i = 0; i < 4; ++i) sa[i] = f32x4{0.f, 0.f, 0.f, 0.f};
            #pragma unroll
            for (int ks = 0; ks < 2; ++ks) {
                const int kt = ks * 32;
                u32x4 qh = fragp<64, 7>(QsH, w * 16 + l15, kt, lhi);
                u32x4 ql = fragp<64, 7>(QsL, w * 16 + l15, kt, lhi);
                #pragma unroll
                for (int nt = 0; nt < 4; ++nt) {
                    u32x4 kh = fragp<64, 7>(KsH, nt * 16 + l15, kt, lhi);
                    u32x4 kl = fragp<64, 7>(KsL, nt * 16 + l15, kt, lhi);
                    sa[nt] = MFMA(qh, kh, sa[nt]);
                    sa[nt] = MFMA(qh, kl, sa[nt]);
                    sa[nt] = MFMA(ql, kh, sa[nt]);
                }
            }
            float sc[4][4];
            #pragma unroll
            for (int nt = 0; nt < 4; ++nt) {
                const float mterm = (1.0f - msk[nt * 16 + l15]) * -1e9f;
                #pragma unroll
                for (int r = 0; r < 4; ++r) sc[nt][r] = sa[nt][r] * 0.125f + mterm;
            }
            #pragma unroll
            for (int r = 0; r < 4; ++r) {
                float m = fmaxf(fmaxf(sc[0][r], sc[1][r]), fmaxf(sc[2][r], sc[3][r]));
                #pragma unroll
                for (int off = 1; off < 16; off <<= 1) m = fmaxf(m, __shfl_xor(m, off));
                float e0 = expf(sc[0][r] - m), e1 = expf(sc[1][r] - m);
                float e2 = expf(sc[2][r] - m), e3 = expf(sc[3][r] - m);
                float s = e0 + e1 + e2 + e3;
                #pragma unroll
                for (int off = 1; off < 16; off <<= 1) s += __shfl_xor(s, off);
                const float inv = 1.0f / s;
                sc[0][r] = e0 * inv; sc[1][r] = e1 * inv;
                sc[2][r] = e2 * inv; sc[3][r] = e3 * inv;
            }
            #pragma unroll
            for (int nt = 0; nt < 4; ++nt) {
                #pragma unroll
                for (int r = 0; r < 4; ++r) {
                    U16 vH, vL; split_hl(sc[nt][r], vH, vL);
                    put16<64, 7>(QsH, w * 16 + lhi * 4 + r, nt * 16 + l15, vH);
                    put16<64, 7>(QsL, w * 16 + lhi * 4 + r, nt * 16 + l15, vL);
                }
            }
        }
        // ------- PV (P own rows; V^T in XB, barriered) + masked row-sum -------
        {
            f32x4 pa[4];
            #pragma unroll
            for (int i = 0; i < 4; ++i) pa[i] = f32x4{0.f, 0.f, 0.f, 0.f};
            #pragma unroll
            for (int ks = 0; ks < 2; ++ks) {
                const int kt = ks * 32;
                u32x4 ph = fragp<64, 7>(QsH, w * 16 + l15, kt, lhi);
                u32x4 pl = fragp<64, 7>(QsL, w * 16 + l15, kt, lhi);
                #pragma unroll
                for (int nt = 0; nt < 4; ++nt) {
                    u32x4 vh = fragp<64, 7>(XBH, nt * 16 + l15, kt, lhi);
                    u32x4 vl = fragp<64, 7>(XBL, nt * 16 + l15, kt, lhi);
                    pa[nt] = MFMA(ph, vh, pa[nt]);
                    pa[nt] = MFMA(ph, vl, pa[nt]);
                    pa[nt] = MFMA(pl, vh, pa[nt]);
                }
            }
            float sarr[4];
            #pragma unroll
            for (int nt = 0; nt < 4; ++nt) {
                float s = 0.f;
                #pragma unroll
                for (int r = 0; r < 4; ++r)
                    s += msk[w * 16 + lhi * 4 + r] * pa[nt][r];
                s += __shfl_xor(s, 16);
                s += __shfl_xor(s, 32);
                sarr[nt] = s;
            }
            // static po indices via uniform branch on h (rule #20)
            if (h == 0) {
                po[0] = sarr[0]; po[1] = sarr[1]; po[2] = sarr[2]; po[3] = sarr[3];
            } else if (h == 1) {
                po[4] = sarr[0]; po[5] = sarr[1]; po[6] = sarr[2]; po[7] = sarr[3];
            } else if (h == 2) {
                po[8] = sarr[0]; po[9] = sarr[1]; po[10] = sarr[2]; po[11] = sarr[3];
            } else {
                po[12] = sarr[0]; po[13] = sarr[1]; po[14] = sarr[2]; po[15] = sarr[3];
            }
        }
        // next top-of-head barrier orders XB rewrites after PV reads
    }

    // ---------------- epilogue: cross-wave pool sum + fp32 out-proj ----------------
    __syncthreads();   // all waves done h=3 scores/PV; Ks region free
    float (*part)[256] = (float(*)[256])KsH;   // 4 KB into the 8 KB plane
    if (lhi == 0) {
        #pragma unroll
        for (int hh = 0; hh < 4; ++hh)
            #pragma unroll
            for (int nt = 0; nt < 4; ++nt)
                part[w][hh * 64 + nt * 16 + l15] = po[hh * 4 + nt];
    }
    __syncthreads();
    {
        float opv = part[0][t] + part[1][t] + part[2][t] + part[3][t];
        part[0][t] = opv;   // own index; becomes the broadcast buffer
    }
    __syncthreads();
    {
        const float* wrow = Wo32 + (size_t)t * 256;
        const float* opool = part[0];
        float s = 0.f;
        #pragma unroll 8
        for (int c = 0; c < 256; c += 4) {
            float4 wv = *(const float4*)(wrow + c);
            s += opool[c] * wv.x + opool[c + 1] * wv.y
               + opool[c + 2] * wv.z + opool[c + 3] * wv.w;
        }
        float m = smsum;
        float val = (s + bo[t] * m) / (m + 1e-10f);
        U16 vH, vL; split_hl(val, vH, vL);
        sent_hi[(size_t)b * 256 + t] = vH;
        sent_lo[(size_t)b * 256 + t] = vL;
    }
    if (t == 0) smask[b] = (smsum > 0.f) ? 1.f : 0.f;
}

// ---- levels 2/3: L in {16, 8}; unchanged (passes, ~30 us total) ----
template <int L>
__global__ __launch_bounds__(256) void mha_small(
    const U16* __restrict__ xh, const U16* __restrict__ xl,
    const float* __restrict__ mk,
    const U16* __restrict__ Wqh, const U16* __restrict__ Wql,
    const float* __restrict__ bqkv,
    const U16* __restrict__ Woh, const U16* __restrict__ Wol,
    const float* __restrict__ bo,
    float* __restrict__ out_f32, U16* __restrict__ out_hi, U16* __restrict__ out_lo,
    float* __restrict__ outmask)
{
    __shared__ __align__(16) U16 xs_h[16*256], xs_l[16*256];
    __shared__ __align__(16) U16 Qh_[16*256], Ql_[16*256];
    __shared__ __align__(16) U16 Kh_[16*256], Kl_[16*256];
    __shared__ __align__(16) U16 Vh_[256*32], Vl_[256*32];
    __shared__ __align__(16) U16 Ph_[4][16*32], Pl_[4][16*32];
    __shared__ __align__(16) U16 Oh_[16*256], Ol_[16*256];
    __shared__ float msk[16];
    __shared__ float smsum;

    const int t = threadIdx.x;
    const int w = t >> 6, l = t & 63, l15 = l & 15, lhi = l >> 4;
    const int b = blockIdx.x;

    if (t < 16) msk[t] = (t < L) ? mk[b*L + t] : 0.f;

    #pragma unroll
    for (int i = 0; i < 2; ++i) {
        int c = i*256 + t;
        int row = c >> 5, c8 = c & 31;
        u32x4 hv = u32x4{0,0,0,0}, lv = u32x4{0,0,0,0};
        if (row < L) {
            hv = *(const u32x4*)(xh + ((size_t)b*L + row)*256 + c8*8);
            lv = *(const u32x4*)(xl + ((size_t)b*L + row)*256 + c8*8);
        }
        int slot = c8 ^ (row & 7);
        *(u32x4*)(xs_h + row*256 + slot*8) = hv;
        *(u32x4*)(xs_l + row*256 + slot*8) = lv;
    }
    #pragma unroll
    for (int i = 0; i < 4; ++i) {
        int c = i*256 + t;
        *(u32x4*)(Vh_ + c*8) = u32x4{0,0,0,0};
        *(u32x4*)(Vl_ + c*8) = u32x4{0,0,0,0};
    }
    *(u32x4*)(&Ph_[0][0] + t*8) = u32x4{0,0,0,0};
    *(u32x4*)(&Pl_[0][0] + t*8) = u32x4{0,0,0,0};
    __syncthreads();
    if (t == 0) { float s = 0.f; for (int i = 0; i < 16; ++i) s += msk[i]; smsum = s; }

    {
        f32x4 acc[12];
        #pragma unroll
        for (int i = 0; i < 12; ++i) acc[i] = f32x4{0.f,0.f,0.f,0.f};
        #pragma unroll 2
        for (int k0 = 0; k0 < 256; k0 += 32) {
            u32x4 ah = fragp<256,7>(xs_h, l15, k0, lhi);
            u32x4 al = fragp<256,7>(xs_l, l15, k0, lhi);
            #pragma unroll
            for (int j = 0; j < 12; ++j) {
                int u = w*12 + j;
                u32x4 wh = *(const u32x4*)(Wqh + (size_t)(u*16 + l15)*256 + k0 + lhi*8);
                u32x4 wl = *(const u32x4*)(Wql + (size_t)(u*16 + l15)*256 + k0 + lhi*8);
                acc[j] = MFMA(ah, wh, acc[j]);
                acc[j] = MFMA(ah, wl, acc[j]);
                acc[j] = MFMA(al, wh, acc[j]);
            }
        }
        #pragma unroll
        for (int j = 0; j < 12; ++j) {
            int u = w*12 + j;
            int mat = u >> 4, cg = u & 15;
            float bias = bqkv[u*16 + l15];
            if (mat < 2) {
                U16* dh = (mat == 0) ? Qh_ : Kh_;
                U16* dl = (mat == 0) ? Ql_ : Kl_;
                #pragma unroll
                for (int r = 0; r < 4; ++r) {
                    U16 vH, vL; split_hl(acc[j][r] + bias, vH, vL);
                    put16<256,7>(dh, lhi*4 + r, cg*16 + l15, vH);
                    put16<256,7>(dl, lhi*4 + r, cg*16 + l15, vL);
                }
            } else {
                U16 h4[4], l4[4];
                #pragma unroll
                for (int r = 0; r < 4; ++r) split_hl(acc[j][r] + bias, h4[r], l4[r]);
                put64<32,3>(Vh_, cg*16 + l15, lhi*4, h4[0],h4[1],h4[2],h4[3]);
                put64<32,3>(Vl_, cg*16 + l15, lhi*4, l4[0],l4[1],l4[2],l4[3]);
            }
        }
    }
    __syncthreads();

    {
        const int h = w;
        f32x4 sa = f32x4{0.f,0.f,0.f,0.f};
        #pragma unroll
        for (int k0 = 0; k0 < 64; k0 += 32) {
            u32x4 qh = fragp<256,7>(Qh_, l15, h*64 + k0, lhi);
            u32x4 ql = fragp<256,7>(Ql_, l15, h*64 + k0, lhi);
            u32x4 kh = fragp<256,7>(Kh_, l15, h*64 + k0, lhi);
            u32x4 kl = fragp<256,7>(Kl_, l15, h*64 + k0, lhi);
            sa = MFMA(qh, kh, sa);
            sa = MFMA(qh, kl, sa);
            sa = MFMA(ql, kh, sa);
        }
        float sc[4];
        float mterm = (1.0f - msk[l15]) * -1e9f;
        #pragma unroll
        for (int r = 0; r < 4; ++r) sc[r] = sa[r] * 0.125f + mterm;
        #pragma unroll
        for (int r = 0; r < 4; ++r) {
            float m = sc[r];
            #pragma unroll
            for (int off = 1; off < 16; off <<= 1) m = fmaxf(m, __shfl_xor(m, off));
            float e = expf(sc[r] - m);
            float s = e;
            #pragma unroll
            for (int off = 1; off < 16; off <<= 1) s += __shfl_xor(s, off);
            sc[r] = e / s;
        }
        #pragma unroll
        for (int r = 0; r < 4; ++r) {
            U16 vH, vL; split_hl(sc[r], vH, vL);
            put16<32,3>(&Ph_[h][0], lhi*4 + r, l15, vH);
            put16<32,3>(&Pl_[h][0], lhi*4 + r, l15, vL);
        }
        f32x4 pa[4];
        #pragma unroll
        for (int i = 0; i < 4; ++i) pa[i] = f32x4{0.f,0.f,0.f,0.f};
        {
            u32x4 ph = fragp<32,3>(&Ph_[h][0], l15, 0, lhi);
            u32x4 pl = fragp<32,3>(&Pl_[h][0], l15, 0, lhi);
            #pragma unroll
            for (int ntl = 0; ntl < 4; ++ntl) {
                u32x4 vh = fragp<32,3>(Vh_, h*64 + ntl*16 + l15, 0, lhi);
                u32x4 vl = fragp<32,3>(Vl_, h*64 + ntl*16 + l15, 0, lhi);
                pa[ntl] = MFMA(ph, vh, pa[ntl]);
                pa[ntl] = MFMA(ph, vl, pa[ntl]);
                pa[ntl] = MFMA(pl, vh, pa[ntl]);
            }
        }
        #pragma unroll
        for (int ntl = 0; ntl < 4; ++ntl) {
            #pragma unroll
            for (int r = 0; r < 4; ++r) {
                U16 vH, vL; split_hl(pa[ntl][r], vH, vL);
                put16<256,7>(Oh_, lhi*4 + r, h*64 + ntl*16 + l15, vH);
                put16<256,7>(Ol_, lhi*4 + r, h*64 + ntl*16 + l15, vL);
            }
        }
    }
    __syncthreads();

    {
        f32x4 acc4[4];
        #pragma unroll
        for (int i = 0; i < 4; ++i) acc4[i] = f32x4{0.f,0.f,0.f,0.f};
        #pragma unroll 2
        for (int k0 = 0; k0 < 256; k0 += 32) {
            u32x4 oh = fragp<256,7>(Oh_, l15, k0, lhi);
            u32x4 ol = fragp<256,7>(Ol_, l15, k0, lhi);
            #pragma unroll
            for (int j = 0; j < 4; ++j) {
                int oc = w*64 + j*16 + l15;
                u32x4 wh = *(const u32x4*)(Woh + (size_t)oc*256 + k0 + lhi*8);
                u32x4 wl = *(const u32x4*)(Wol + (size_t)oc*256 + k0 + lhi*8);
                acc4[j] = MFMA(oh, wh, acc4[j]);
                acc4[j] = MFMA(oh, wl, acc4[j]);
                acc4[j] = MFMA(ol, wh, acc4[j]);
            }
        }
        float msum = smsum;
        #pragma unroll
        for (int j = 0; j < 4; ++j) {
            float s = 0.f;
            #pragma unroll
            for (int r = 0; r < 4; ++r) s += msk[lhi*4 + r] * acc4[j][r];
            s += __shfl_xor(s, 16);
            s += __shfl_xor(s, 32);
            if (lhi == 0) {
                int col = w*64 + j*16 + l15;
                float val = (s + bo[col] * msum) / (msum + 1e-10f);
                if (out_f32) out_f32[(size_t)b*256 + col] = val;
                if (out_hi) {
                    U16 vH, vL; split_hl(val, vH, vL);
                    out_hi[(size_t)b*256 + col] = vH;
                    out_lo[(size_t)b*256 + col] = vL;
                }
            }
        }
    }
    if (t == 0 && outmask) outmask[b] = (smsum > 0.f) ? 1.f : 0.f;
}

extern "C" void kernel_launch(void* const* d_in, const int* in_sizes, int n_in,
                              void* d_out, int out_size, void* d_ws, size_t ws_size,
                              hipStream_t stream) {
    (void)in_sizes; (void)n_in; (void)out_size; (void)ws_size;
    const float* we  = (const float*)d_in[0];
    const int*   am  = (const int*)d_in[1];
    const float* wW  = (const float*)d_in[2];
    const float* wb  = (const float*)d_in[3];
    const float* wO  = (const float*)d_in[4];
    const float* wob = (const float*)d_in[5];
    const float* sW  = (const float*)d_in[6];
    const float* sb  = (const float*)d_in[7];
    const float* sO  = (const float*)d_in[8];
    const float* sob = (const float*)d_in[9];
    const float* cW  = (const float*)d_in[10];
    const float* cb  = (const float*)d_in[11];
    const float* cO  = (const float*)d_in[12];
    const float* cob = (const float*)d_in[13];

    U16* p = (U16*)d_ws;
    U16* sent_hi = p; p += 2048*256;
    U16* sent_lo = p; p += 2048*256;
    U16* sect_hi = p; p += 128*256;
    U16* sect_lo = p; p += 128*256;
    U16* w1qh = p; p += 768*256;  U16* w1ql = p; p += 768*256;
    U16* w1oh = p; p += 256*256;  U16* w1ol = p; p += 256*256;
    U16* w2qh = p; p += 768*256;  U16* w2ql = p; p += 768*256;
    U16* w2oh = p; p += 256*256;  U16* w2ol = p; p += 256*256;
    U16* w3qh = p; p += 768*256;  U16* w3ql = p; p += 768*256;
    U16* w3oh = p; p += 256*256;  U16* w3ol = p; p += 256*256;
    float* smaskb = (float*)p;
    float* cmaskb = smaskb + 2048;

    convert_w<<<768, 256, 0, stream>>>(wW, wO, w1qh, w1ql, w1oh, w1ol);
    convert_w<<<768, 256, 0, stream>>>(sW, sO, w2qh, w2ql, w2oh, w2ol);
    convert_w<<<768, 256, 0, stream>>>(cW, cO, w3qh, w3ql, w3oh, w3ol);
    word_mfma<<<2048, 256, 0, stream>>>(we, am, w1qh, w1ql, wb, wO, wob,
                                        sent_hi, sent_lo, smaskb);
    mha_small<16><<<128, 256, 0, stream>>>(sent_hi, sent_lo, smaskb,
                                           w2qh, w2ql, sb, w2oh, w2ol, sob,
                                           nullptr, sect_hi, sect_lo, cmaskb);
    mha_small<8><<<16, 256, 0, stream>>>(sect_hi, sect_lo, cmaskb,
                                         w3qh, w3ql, cb, w3oh, w3ol, cob,
                                         (float*)d_out, nullptr, nullptr, nullptr);
}

// Round 18
// 462.284 us; speedup vs baseline: 1.1785x; 1.1785x over previous
//
#include <hip/hip_runtime.h>
#include <hip/hip_bf16.h>

// Hierarchical attention, 3 levels. Split-bf16 (hi/lo) MFMA for QKV/scores/PV;
// out-proj commuted with masked mean pool (exact fp32 matvec epilogue).
// r18 = r16 (hi/lo u16 planes, perm-free frags, (256,2) no-spill) with the
// kc-loop double-buffered (XA=even chunks, XB=odd chunks/V^T): phase =
// {ds_write held regs -> other buf; load chunk (kc+2)&3 -> regs; MFMA; 1 sync}.
// x is head-invariant so the pipeline is fully uniform (no conditionals --
// r17's spill suspect). Register lifetimes identical to r16. Barriers 10->6
// per head. LDS 64.3 KB -> 2 blocks/CU.

typedef short bf16x8 __attribute__((ext_vector_type(8)));
typedef float f32x4 __attribute__((ext_vector_type(4)));
typedef unsigned int u32x4 __attribute__((ext_vector_type(4)));
typedef unsigned short U16;
typedef unsigned int U32;

__device__ __forceinline__ U16 f2bf(float f) {
    __hip_bfloat16 b = __float2bfloat16(f);   // HW cvt (RNE)
    return __builtin_bit_cast(U16, b);
}
__device__ __forceinline__ void split_hl(float f, U16& h, U16& l) {
    h = f2bf(f);
    float hf = __builtin_bit_cast(float, (U32)h << 16);
    l = f2bf(f - hf);
}

#define MFMA(A, B, C) __builtin_amdgcn_mfma_f32_16x16x32_bf16( \
    __builtin_bit_cast(bf16x8, A), __builtin_bit_cast(bf16x8, B), C, 0, 0, 0)

// u16 plane helpers. RS = row stride (u16 units), SW = row swizzle mask.
// Element k of row r lives at 16B-slot ((k>>3) ^ (r & SW)).
template <int RS, int SW>
__device__ __forceinline__ u32x4 fragp(const U16* base, int row, int k, int lhi) {
    int slot = ((k >> 3) + lhi) ^ (row & SW);
    return *(const u32x4*)(base + row * RS + slot * 8);
}
template <int RS, int SW>
__device__ __forceinline__ void put16(U16* base, int row, int col, U16 v) {
    int slot = (col >> 3) ^ (row & SW);
    base[row * RS + slot * 8 + (col & 7)] = v;
}
template <int RS, int SW>
__device__ __forceinline__ void put64(U16* base, int row, int col0,
                                      U16 v0, U16 v1, U16 v2, U16 v3) {
    int slot = (col0 >> 3) ^ (row & SW);
    U32* p = (U32*)(base + row * RS + slot * 8 + (col0 & 7));
    p[0] = (U32)v0 | ((U32)v1 << 16);
    p[1] = (U32)v2 | ((U32)v3 << 16);
}

// stage 8 consecutive elements (cols c8*8..+7) of one row into hi/lo planes
__device__ __forceinline__ void stage8(U16* ph, U16* pl, int row, int c8,
                                       float4 a, float4 b) {
    U16 h[8], l[8];
    split_hl(a.x, h[0], l[0]); split_hl(a.y, h[1], l[1]);
    split_hl(a.z, h[2], l[2]); split_hl(a.w, h[3], l[3]);
    split_hl(b.x, h[4], l[4]); split_hl(b.y, h[5], l[5]);
    split_hl(b.z, h[6], l[6]); split_hl(b.w, h[7], l[7]);
    u32x4 hv, lv;
    #pragma unroll
    for (int q = 0; q < 4; ++q) {
        hv[q] = (U32)h[2*q] | ((U32)h[2*q+1] << 16);
        lv[q] = (U32)l[2*q] | ((U32)l[2*q+1] << 16);
    }
    const int slot = c8 ^ (row & 7);
    *(u32x4*)(ph + row * 64 + slot * 8) = hv;
    *(u32x4*)(pl + row * 64 + slot * 8) = lv;
}

__global__ __launch_bounds__(256) void convert_w(
    const float* __restrict__ Wq, const float* __restrict__ Wo,
    U16* __restrict__ qh, U16* __restrict__ ql,
    U16* __restrict__ oh, U16* __restrict__ ol)
{
    int i = blockIdx.x * 256 + threadIdx.x;
    if (i < 768 * 256) { U16 h, l; split_hl(Wq[i], h, l); qh[i] = h; ql[i] = l; }
    if (i < 256 * 256) { U16 h, l; split_hl(Wo[i], h, l); oh[i] = h; ol[i] = l; }
}

// ---- word level: 1 block = 1 sequence (L=64), 256 threads = 4 waves ----
__global__ __launch_bounds__(256, 2) void word_mfma(
    const float* __restrict__ x, const int* __restrict__ am,
    const U16* __restrict__ Wqh, const U16* __restrict__ Wql,
    const float* __restrict__ bqkv,
    const float* __restrict__ Wo32,   // fp32 [256][256]
    const float* __restrict__ bo,
    U16* __restrict__ sent_hi, U16* __restrict__ sent_lo,
    float* __restrict__ smask)
{
    __shared__ __align__(16) U16 QsH[64 * 64], QsL[64 * 64];  // Q, later P
    __shared__ __align__(16) U16 KsH[64 * 64], KsL[64 * 64];  // K; end: scratch
    __shared__ __align__(16) U16 XAH[64 * 64], XAL[64 * 64];  // even chunks
    __shared__ __align__(16) U16 XBH[64 * 64], XBL[64 * 64];  // odd chunks; V^T
    __shared__ float msk[64];
    __shared__ float smsum;

    const int t = threadIdx.x;
    const int w = t >> 6, l = t & 63, l15 = l & 15, lhi = l >> 4;
    const int b = blockIdx.x;
    const float* xb = x + (size_t)b * 16384;

    if (t < 64) msk[t] = (float)am[b * 64 + t];

    const int r0 = t >> 3, c8 = t & 7;
    const int r1 = r0 + 32;

    // prologue: chunk0 -> XA; chunk1 -> held regs
    float4 s00, s01, s10, s11;
    {
        s00 = *(const float4*)(xb + r0 * 256 + c8 * 8);
        s01 = *(const float4*)(xb + r0 * 256 + c8 * 8 + 4);
        s10 = *(const float4*)(xb + r1 * 256 + c8 * 8);
        s11 = *(const float4*)(xb + r1 * 256 + c8 * 8 + 4);
        stage8(XAH, XAL, r0, c8, s00, s01);
        stage8(XAH, XAL, r1, c8, s10, s11);
        s00 = *(const float4*)(xb + r0 * 256 + 64 + c8 * 8);
        s01 = *(const float4*)(xb + r0 * 256 + 64 + c8 * 8 + 4);
        s10 = *(const float4*)(xb + r1 * 256 + 64 + c8 * 8);
        s11 = *(const float4*)(xb + r1 * 256 + 64 + c8 * 8 + 4);
    }

    float po[16];   // pooled-O partials, static-indexed only (uniform h branch)

    #pragma unroll 1
    for (int h = 0; h < 4; ++h) {
        __syncthreads();   // top-of-head: PV reads done; staged chunk0 visible
        f32x4 acc[3][4];
        #pragma unroll
        for (int j = 0; j < 3; ++j)
            #pragma unroll
            for (int mt = 0; mt < 4; ++mt) acc[j][mt] = f32x4{0.f, 0.f, 0.f, 0.f};

        #pragma unroll
        for (int kc = 0; kc < 4; ++kc) {
            // write held regs (chunk (kc+1)&3) into the buffer NOT being read
            U16* sth = (kc & 1) ? XAH : XBH;
            U16* stl = (kc & 1) ? XAL : XBL;
            stage8(sth, stl, r0, c8, s00, s01);
            stage8(sth, stl, r1, c8, s10, s11);
            // load chunk (kc+2)&3 (head-invariant x -> fully uniform pipeline)
            const int ck = ((kc + 2) & 3) * 64;
            s00 = *(const float4*)(xb + r0 * 256 + ck + c8 * 8);
            s01 = *(const float4*)(xb + r0 * 256 + ck + c8 * 8 + 4);
            s10 = *(const float4*)(xb + r1 * 256 + ck + c8 * 8);
            s11 = *(const float4*)(xb + r1 * 256 + ck + c8 * 8 + 4);
            // MFMA chunk kc from buf kc&1 (staged last phase, barrier'd)
            const U16* xph = (kc & 1) ? XBH : XAH;
            const U16* xpl = (kc & 1) ? XBL : XAL;
            #pragma unroll
            for (int ks = 0; ks < 2; ++ks) {
                const int kt = ks * 32;              // k within 64-wide tile
                const int kk = kc * 64 + kt + lhi * 8;
                const size_t wr0 = (size_t)(          h * 64 + w * 16 + l15) * 256 + kk;
                const size_t wr1 = (size_t)(256     + h * 64 + w * 16 + l15) * 256 + kk;
                const size_t wr2 = (size_t)(512     + h * 64 + w * 16 + l15) * 256 + kk;
                u32x4 wh0 = *(const u32x4*)(Wqh + wr0);
                u32x4 wl0 = *(const u32x4*)(Wql + wr0);
                u32x4 wh1 = *(const u32x4*)(Wqh + wr1);
                u32x4 wl1 = *(const u32x4*)(Wql + wr1);
                u32x4 wh2 = *(const u32x4*)(Wqh + wr2);
                u32x4 wl2 = *(const u32x4*)(Wql + wr2);
                #pragma unroll
                for (int mt = 0; mt < 4; ++mt) {
                    u32x4 xh = fragp<64, 7>(xph, mt * 16 + l15, kt, lhi);
                    u32x4 xl = fragp<64, 7>(xpl, mt * 16 + l15, kt, lhi);
                    acc[0][mt] = MFMA(xh, wh0, acc[0][mt]);
                    acc[0][mt] = MFMA(xh, wl0, acc[0][mt]);
                    acc[0][mt] = MFMA(xl, wh0, acc[0][mt]);
                    acc[1][mt] = MFMA(xh, wh1, acc[1][mt]);
                    acc[1][mt] = MFMA(xh, wl1, acc[1][mt]);
                    acc[1][mt] = MFMA(xl, wh1, acc[1][mt]);
                    acc[2][mt] = MFMA(xh, wh2, acc[2][mt]);
                    acc[2][mt] = MFMA(xh, wl2, acc[2][mt]);
                    acc[2][mt] = MFMA(xl, wh2, acc[2][mt]);
                }
            }
            __syncthreads();   // phase end: chunk kc reads + chunk kc+1 writes done
        }
        // ---- write Q / K planes + V^T into XB (chunk-3 reads drained) ----
        {
            const float bQ = bqkv[      h * 64 + w * 16 + l15];
            const float bK = bqkv[256 + h * 64 + w * 16 + l15];
            #pragma unroll
            for (int mt = 0; mt < 4; ++mt) {
                #pragma unroll
                for (int r = 0; r < 4; ++r) {
                    U16 vH, vL;
                    split_hl(acc[0][mt][r] + bQ, vH, vL);
                    put16<64, 7>(QsH, mt * 16 + lhi * 4 + r, w * 16 + l15, vH);
                    put16<64, 7>(QsL, mt * 16 + lhi * 4 + r, w * 16 + l15, vL);
                    split_hl(acc[1][mt][r] + bK, vH, vL);
                    put16<64, 7>(KsH, mt * 16 + lhi * 4 + r, w * 16 + l15, vH);
                    put16<64, 7>(KsL, mt * 16 + lhi * 4 + r, w * 16 + l15, vL);
                }
            }
            const float bV = bqkv[512 + h * 64 + w * 16 + l15];
            const int d = w * 16 + l15;
            #pragma unroll
            for (int mt = 0; mt < 4; ++mt) {
                U16 h4[4], l4[4];
                #pragma unroll
                for (int r = 0; r < 4; ++r)
                    split_hl(acc[2][mt][r] + bV, h4[r], l4[r]);
                put64<64, 7>(XBH, d, mt * 16 + lhi * 4, h4[0], h4[1], h4[2], h4[3]);
                put64<64, 7>(XBL, d, mt * 16 + lhi * 4, l4[0], l4[1], l4[2], l4[3]);
            }
        }
        __syncthreads();   // Q, K, V^T ready
        if (h == 0 && t == 0) {
            float s = 0.f;
            for (int i = 0; i < 64; ++i) s += msk[i];
            smsum = s;
        }

        // ------- scores + softmax + P (wave w owns row-tile w) -------
        {
            f32x4 sa[4];
            #pragma unroll
            for (int i = 0; i < 4; ++i) sa[i] = f32x4{0.f, 0.f, 0.f, 0.f};
            #pragma unroll
            for (int ks = 0; ks < 2; ++ks) {
                const int kt = ks * 32;
                u32x4 qh = fragp<64, 7>(QsH, w * 16 + l15, kt, lhi);
                u32x4 ql = fragp<64, 7>(QsL, w * 16 + l15, kt, lhi);
                #pragma unroll
                for (int nt = 0; nt < 4; ++nt) {
                    u32x4 kh = fragp<64, 7>(KsH, nt * 16 + l15, kt, lhi);
                    u32x4 kl = fragp<64, 7>(KsL, nt * 16 + l15, kt, lhi);
                    sa[nt] = MFMA(qh, kh, sa[nt]);
                    sa[nt] = MFMA(qh, kl, sa[nt]);
                    sa[nt] = MFMA(ql, kh, sa[nt]);
                }
            }
            float sc[4][4];
            #pragma unroll
            for (int nt = 0; nt < 4; ++nt) {
                const float mterm = (1.0f - msk[nt * 16 + l15]) * -1e9f;
                #pragma unroll
                for (int r = 0; r < 4; ++r) sc[nt][r] = sa[nt][r] * 0.125f + mterm;
            }
            #pragma unroll
            for (int r = 0; r < 4; ++r) {
                float m = fmaxf(fmaxf(sc[0][r], sc[1][r]), fmaxf(sc[2][r], sc[3][r]));
                #pragma unroll
                for (int off = 1; off < 16; off <<= 1) m = fmaxf(m, __shfl_xor(m, off));
                float e0 = expf(sc[0][r] - m), e1 = expf(sc[1][r] - m);
                float e2 = expf(sc[2][r] - m), e3 = expf(sc[3][r] - m);
                float s = e0 + e1 + e2 + e3;
                #pragma unroll
                for (int off = 1; off < 16; off <<= 1) s += __shfl_xor(s, off);
                const float inv = 1.0f / s;
                sc[0][r] = e0 * inv; sc[1][r] = e1 * inv;
                sc[2][r] = e2 * inv; sc[3][r] = e3 * inv;
            }
            #pragma unroll
            for (int nt = 0; nt < 4; ++nt) {
                #pragma unroll
                for (int r = 0; r < 4; ++r) {
                    U16 vH, vL; split_hl(sc[nt][r], vH, vL);
                    put16<64, 7>(QsH, w * 16 + lhi * 4 + r, nt * 16 + l15, vH);
                    put16<64, 7>(QsL, w * 16 + lhi * 4 + r, nt * 16 + l15, vL);
                }
            }
        }
        // ------- PV (P own rows; V^T in XB, barriered) + masked row-sum -------
        {
            f32x4 pa[4];
            #pragma unroll
            for (int i = 0; i < 4; ++i) pa[i] = f32x4{0.f, 0.f, 0.f, 0.f};
            #pragma unroll
            for (int ks = 0; ks < 2; ++ks) {
                const int kt = ks * 32;
                u32x4 ph = fragp<64, 7>(QsH, w * 16 + l15, kt, lhi);
                u32x4 pl = fragp<64, 7>(QsL, w * 16 + l15, kt, lhi);
                #pragma unroll
                for (int nt = 0; nt < 4; ++nt) {
                    u32x4 vh = fragp<64, 7>(XBH, nt * 16 + l15, kt, lhi);
                    u32x4 vl = fragp<64, 7>(XBL, nt * 16 + l15, kt, lhi);
                    pa[nt] = MFMA(ph, vh, pa[nt]);
                    pa[nt] = MFMA(ph, vl, pa[nt]);
                    pa[nt] = MFMA(pl, vh, pa[nt]);
                }
            }
            float sarr[4];
            #pragma unroll
            for (int nt = 0; nt < 4; ++nt) {
                float s = 0.f;
                #pragma unroll
                for (int r = 0; r < 4; ++r)
                    s += msk[w * 16 + lhi * 4 + r] * pa[nt][r];
                s += __shfl_xor(s, 16);
                s += __shfl_xor(s, 32);
                sarr[nt] = s;
            }
            // static po indices via uniform branch on h (rule #20)
            if (h == 0) {
                po[0] = sarr[0]; po[1] = sarr[1]; po[2] = sarr[2]; po[3] = sarr[3];
            } else if (h == 1) {
                po[4] = sarr[0]; po[5] = sarr[1]; po[6] = sarr[2]; po[7] = sarr[3];
            } else if (h == 2) {
                po[8] = sarr[0]; po[9] = sarr[1]; po[10] = sarr[2]; po[11] = sarr[3];
            } else {
                po[12] = sarr[0]; po[13] = sarr[1]; po[14] = sarr[2]; po[15] = sarr[3];
            }
        }
        // next top-of-head barrier orders XB rewrites after PV reads
    }

    // ---------------- epilogue: cross-wave pool sum + fp32 out-proj ----------------
    __syncthreads();   // all waves done h=3 scores/PV; Ks region free
    float (*part)[256] = (float(*)[256])KsH;   // 4 KB into the 8 KB plane
    if (lhi == 0) {
        #pragma unroll
        for (int hh = 0; hh < 4; ++hh)
            #pragma unroll
            for (int nt = 0; nt < 4; ++nt)
                part[w][hh * 64 + nt * 16 + l15] = po[hh * 4 + nt];
    }
    __syncthreads();
    {
        float opv = part[0][t] + part[1][t] + part[2][t] + part[3][t];
        part[0][t] = opv;   // own index; becomes the broadcast buffer
    }
    __syncthreads();
    {
        const float* wrow = Wo32 + (size_t)t * 256;
        const float* opool = part[0];
        float s = 0.f;
        #pragma unroll 8
        for (int c = 0; c < 256; c += 4) {
            float4 wv = *(const float4*)(wrow + c);
            s += opool[c] * wv.x + opool[c + 1] * wv.y
               + opool[c + 2] * wv.z + opool[c + 3] * wv.w;
        }
        float m = smsum;
        float val = (s + bo[t] * m) / (m + 1e-10f);
        U16 vH, vL; split_hl(val, vH, vL);
        sent_hi[(size_t)b * 256 + t] = vH;
        sent_lo[(size_t)b * 256 + t] = vL;
    }
    if (t == 0) smask[b] = (smsum > 0.f) ? 1.f : 0.f;
}

// ---- levels 2/3: L in {16, 8}; unchanged (passes, ~30 us total) ----
template <int L>
__global__ __launch_bounds__(256) void mha_small(
    const U16* __restrict__ xh, const U16* __restrict__ xl,
    const float* __restrict__ mk,
    const U16* __restrict__ Wqh, const U16* __restrict__ Wql,
    const float* __restrict__ bqkv,
    const U16* __restrict__ Woh, const U16* __restrict__ Wol,
    const float* __restrict__ bo,
    float* __restrict__ out_f32, U16* __restrict__ out_hi, U16* __restrict__ out_lo,
    float* __restrict__ outmask)
{
    __shared__ __align__(16) U16 xs_h[16*256], xs_l[16*256];
    __shared__ __align__(16) U16 Qh_[16*256], Ql_[16*256];
    __shared__ __align__(16) U16 Kh_[16*256], Kl_[16*256];
    __shared__ __align__(16) U16 Vh_[256*32], Vl_[256*32];
    __shared__ __align__(16) U16 Ph_[4][16*32], Pl_[4][16*32];
    __shared__ __align__(16) U16 Oh_[16*256], Ol_[16*256];
    __shared__ float msk[16];
    __shared__ float smsum;

    const int t = threadIdx.x;
    const int w = t >> 6, l = t & 63, l15 = l & 15, lhi = l >> 4;
    const int b = blockIdx.x;

    if (t < 16) msk[t] = (t < L) ? mk[b*L + t] : 0.f;

    #pragma unroll
    for (int i = 0; i < 2; ++i) {
        int c = i*256 + t;
        int row = c >> 5, c8 = c & 31;
        u32x4 hv = u32x4{0,0,0,0}, lv = u32x4{0,0,0,0};
        if (row < L) {
            hv = *(const u32x4*)(xh + ((size_t)b*L + row)*256 + c8*8);
            lv = *(const u32x4*)(xl + ((size_t)b*L + row)*256 + c8*8);
        }
        int slot = c8 ^ (row & 7);
        *(u32x4*)(xs_h + row*256 + slot*8) = hv;
        *(u32x4*)(xs_l + row*256 + slot*8) = lv;
    }
    #pragma unroll
    for (int i = 0; i < 4; ++i) {
        int c = i*256 + t;
        *(u32x4*)(Vh_ + c*8) = u32x4{0,0,0,0};
        *(u32x4*)(Vl_ + c*8) = u32x4{0,0,0,0};
    }
    *(u32x4*)(&Ph_[0][0] + t*8) = u32x4{0,0,0,0};
    *(u32x4*)(&Pl_[0][0] + t*8) = u32x4{0,0,0,0};
    __syncthreads();
    if (t == 0) { float s = 0.f; for (int i = 0; i < 16; ++i) s += msk[i]; smsum = s; }

    {
        f32x4 acc[12];
        #pragma unroll
        for (int i = 0; i < 12; ++i) acc[i] = f32x4{0.f,0.f,0.f,0.f};
        #pragma unroll 2
        for (int k0 = 0; k0 < 256; k0 += 32) {
            u32x4 ah = fragp<256,7>(xs_h, l15, k0, lhi);
            u32x4 al = fragp<256,7>(xs_l, l15, k0, lhi);
            #pragma unroll
            for (int j = 0; j < 12; ++j) {
                int u = w*12 + j;
                u32x4 wh = *(const u32x4*)(Wqh + (size_t)(u*16 + l15)*256 + k0 + lhi*8);
                u32x4 wl = *(const u32x4*)(Wql + (size_t)(u*16 + l15)*256 + k0 + lhi*8);
                acc[j] = MFMA(ah, wh, acc[j]);
                acc[j] = MFMA(ah, wl, acc[j]);
                acc[j] = MFMA(al, wh, acc[j]);
            }
        }
        #pragma unroll
        for (int j = 0; j < 12; ++j) {
            int u = w*12 + j;
            int mat = u >> 4, cg = u & 15;
            float bias = bqkv[u*16 + l15];
            if (mat < 2) {
                U16* dh = (mat == 0) ? Qh_ : Kh_;
                U16* dl = (mat == 0) ? Ql_ : Kl_;
                #pragma unroll
                for (int r = 0; r < 4; ++r) {
                    U16 vH, vL; split_hl(acc[j][r] + bias, vH, vL);
                    put16<256,7>(dh, lhi*4 + r, cg*16 + l15, vH);
                    put16<256,7>(dl, lhi*4 + r, cg*16 + l15, vL);
                }
            } else {
                U16 h4[4], l4[4];
                #pragma unroll
                for (int r = 0; r < 4; ++r) split_hl(acc[j][r] + bias, h4[r], l4[r]);
                put64<32,3>(Vh_, cg*16 + l15, lhi*4, h4[0],h4[1],h4[2],h4[3]);
                put64<32,3>(Vl_, cg*16 + l15, lhi*4, l4[0],l4[1],l4[2],l4[3]);
            }
        }
    }
    __syncthreads();

    {
        const int h = w;
        f32x4 sa = f32x4{0.f,0.f,0.f,0.f};
        #pragma unroll
        for (int k0 = 0; k0 < 64; k0 += 32) {
            u32x4 qh = fragp<256,7>(Qh_, l15, h*64 + k0, lhi);
            u32x4 ql = fragp<256,7>(Ql_, l15, h*64 + k0, lhi);
            u32x4 kh = fragp<256,7>(Kh_, l15, h*64 + k0, lhi);
            u32x4 kl = fragp<256,7>(Kl_, l15, h*64 + k0, lhi);
            sa = MFMA(qh, kh, sa);
            sa = MFMA(qh, kl, sa);
            sa = MFMA(ql, kh, sa);
        }
        float sc[4];
        float mterm = (1.0f - msk[l15]) * -1e9f;
        #pragma unroll
        for (int r = 0; r < 4; ++r) sc[r] = sa[r] * 0.125f + mterm;
        #pragma unroll
        for (int r = 0; r < 4; ++r) {
            float m = sc[r];
            #pragma unroll
            for (int off = 1; off < 16; off <<= 1) m = fmaxf(m, __shfl_xor(m, off));
            float e = expf(sc[r] - m);
            float s = e;
            #pragma unroll
            for (int off = 1; off < 16; off <<= 1) s += __shfl_xor(s, off);
            sc[r] = e / s;
        }
        #pragma unroll
        for (int r = 0; r < 4; ++r) {
            U16 vH, vL; split_hl(sc[r], vH, vL);
            put16<32,3>(&Ph_[h][0], lhi*4 + r, l15, vH);
            put16<32,3>(&Pl_[h][0], lhi*4 + r, l15, vL);
        }
        f32x4 pa[4];
        #pragma unroll
        for (int i = 0; i < 4; ++i) pa[i] = f32x4{0.f,0.f,0.f,0.f};
        {
            u32x4 ph = fragp<32,3>(&Ph_[h][0], l15, 0, lhi);
            u32x4 pl = fragp<32,3>(&Pl_[h][0], l15, 0, lhi);
            #pragma unroll
            for (int ntl = 0; ntl < 4; ++ntl) {
                u32x4 vh = fragp<32,3>(Vh_, h*64 + ntl*16 + l15, 0, lhi);
                u32x4 vl = fragp<32,3>(Vl_, h*64 + ntl*16 + l15, 0, lhi);
                pa[ntl] = MFMA(ph, vh, pa[ntl]);
                pa[ntl] = MFMA(ph, vl, pa[ntl]);
                pa[ntl] = MFMA(pl, vh, pa[ntl]);
            }
        }
        #pragma unroll
        for (int ntl = 0; ntl < 4; ++ntl) {
            #pragma unroll
            for (int r = 0; r < 4; ++r) {
                U16 vH, vL; split_hl(pa[ntl][r], vH, vL);
                put16<256,7>(Oh_, lhi*4 + r, h*64 + ntl*16 + l15, vH);
                put16<256,7>(Ol_, lhi*4 + r, h*64 + ntl*16 + l15, vL);
            }
        }
    }
    __syncthreads();

    {
        f32x4 acc4[4];
        #pragma unroll
        for (int i = 0; i < 4; ++i) acc4[i] = f32x4{0.f,0.f,0.f,0.f};
        #pragma unroll 2
        for (int k0 = 0; k0 < 256; k0 += 32) {
            u32x4 oh = fragp<256,7>(Oh_, l15, k0, lhi);
            u32x4 ol = fragp<256,7>(Ol_, l15, k0, lhi);
            #pragma unroll
            for (int j = 0; j < 4; ++j) {
                int oc = w*64 + j*16 + l15;
                u32x4 wh = *(const u32x4*)(Woh + (size_t)oc*256 + k0 + lhi*8);
                u32x4 wl = *(const u32x4*)(Wol + (size_t)oc*256 + k0 + lhi*8);
                acc4[j] = MFMA(oh, wh, acc4[j]);
                acc4[j] = MFMA(oh, wl, acc4[j]);
                acc4[j] = MFMA(ol, wh, acc4[j]);
            }
        }
        float msum = smsum;
        #pragma unroll
        for (int j = 0; j < 4; ++j) {
            float s = 0.f;
            #pragma unroll
            for (int r = 0; r < 4; ++r) s += msk[lhi*4 + r] * acc4[j][r];
            s += __shfl_xor(s, 16);
            s += __shfl_xor(s, 32);
            if (lhi == 0) {
                int col = w*64 + j*16 + l15;
                float val = (s + bo[col] * msum) / (msum + 1e-10f);
                if (out_f32) out_f32[(size_t)b*256 + col] = val;
                if (out_hi) {
                    U16 vH, vL; split_hl(val, vH, vL);
                    out_hi[(size_t)b*256 + col] = vH;
                    out_lo[(size_t)b*256 + col] = vL;
                }
            }
        }
    }
    if (t == 0 && outmask) outmask[b] = (smsum > 0.f) ? 1.f : 0.f;
}

extern "C" void kernel_launch(void* const* d_in, const int* in_sizes, int n_in,
                              void* d_out, int out_size, void* d_ws, size_t ws_size,
                              hipStream_t stream) {
    (void)in_sizes; (void)n_in; (void)out_size; (void)ws_size;
    const float* we  = (const float*)d_in[0];
    const int*   am  = (const int*)d_in[1];
    const float* wW  = (const float*)d_in[2];
    const float* wb  = (const float*)d_in[3];
    const float* wO  = (const float*)d_in[4];
    const float* wob = (const float*)d_in[5];
    const float* sW  = (const float*)d_in[6];
    const float* sb  = (const float*)d_in[7];
    const float* sO  = (const float*)d_in[8];
    const float* sob = (const float*)d_in[9];
    const float* cW  = (const float*)d_in[10];
    const float* cb  = (const float*)d_in[11];
    const float* cO  = (const float*)d_in[12];
    const float* cob = (const float*)d_in[13];

    U16* p = (U16*)d_ws;
    U16* sent_hi = p; p += 2048*256;
    U16* sent_lo = p; p += 2048*256;
    U16* sect_hi = p; p += 128*256;
    U16* sect_lo = p; p += 128*256;
    U16* w1qh = p; p += 768*256;  U16* w1ql = p; p += 768*256;
    U16* w1oh = p; p += 256*256;  U16* w1ol = p; p += 256*256;
    U16* w2qh = p; p += 768*256;  U16* w2ql = p; p += 768*256;
    U16* w2oh = p; p += 256*256;  U16* w2ol = p; p += 256*256;
    U16* w3qh = p; p += 768*256;  U16* w3ql = p; p += 768*256;
    U16* w3oh = p; p += 256*256;  U16* w3ol = p; p += 256*256;
    float* smaskb = (float*)p;
    float* cmaskb = smaskb + 2048;

    convert_w<<<768, 256, 0, stream>>>(wW, wO, w1qh, w1ql, w1oh, w1ol);
    convert_w<<<768, 256, 0, stream>>>(sW, sO, w2qh, w2ql, w2oh, w2ol);
    convert_w<<<768, 256, 0, stream>>>(cW, cO, w3qh, w3ql, w3oh, w3ol);
    word_mfma<<<2048, 256, 0, stream>>>(we, am, w1qh, w1ql, wb, wO, wob,
                                        sent_hi, sent_lo, smaskb);
    mha_small<16><<<128, 256, 0, stream>>>(sent_hi, sent_lo, smaskb,
                                           w2qh, w2ql, sb, w2oh, w2ol, sob,
                                           nullptr, sect_hi, sect_lo, cmaskb);
    mha_small<8><<<16, 256, 0, stream>>>(sect_hi, sect_lo, cmaskb,
                                         w3qh, w3ql, cb, w3oh, w3ol, cob,
                                         (float*)d_out, nullptr, nullptr, nullptr);
}

// Round 19
// 408.486 us; speedup vs baseline: 1.3337x; 1.1317x over previous
//
#include <hip/hip_runtime.h>
#include <hip/hip_bf16.h>

// Hierarchical attention, 3 levels. Split-bf16 (hi/lo) MFMA for QKV/scores/PV;
// out-proj commuted with masked mean pool (exact fp32 matvec epilogue).
// r19 = r16 EXACT (best verified: word 365us / total 415us; hi/lo u16 planes,
// perm-free frags, loop-swapped QKV, prefetch staging, VX aliasing, (256,2)
// no-spill) + the 3 convert_w launches fused into 1.
// r17/r18 lesson: any deeper pipeline spills at this register budget.

typedef short bf16x8 __attribute__((ext_vector_type(8)));
typedef float f32x4 __attribute__((ext_vector_type(4)));
typedef unsigned int u32x4 __attribute__((ext_vector_type(4)));
typedef unsigned short U16;
typedef unsigned int U32;

__device__ __forceinline__ U16 f2bf(float f) {
    __hip_bfloat16 b = __float2bfloat16(f);   // HW cvt (RNE)
    return __builtin_bit_cast(U16, b);
}
__device__ __forceinline__ void split_hl(float f, U16& h, U16& l) {
    h = f2bf(f);
    float hf = __builtin_bit_cast(float, (U32)h << 16);
    l = f2bf(f - hf);
}

#define MFMA(A, B, C) __builtin_amdgcn_mfma_f32_16x16x32_bf16( \
    __builtin_bit_cast(bf16x8, A), __builtin_bit_cast(bf16x8, B), C, 0, 0, 0)

// u16 plane helpers. RS = row stride (u16 units), SW = row swizzle mask.
// Element k of row r lives at 16B-slot ((k>>3) ^ (r & SW)).
template <int RS, int SW>
__device__ __forceinline__ u32x4 fragp(const U16* base, int row, int k, int lhi) {
    int slot = ((k >> 3) + lhi) ^ (row & SW);
    return *(const u32x4*)(base + row * RS + slot * 8);
}
template <int RS, int SW>
__device__ __forceinline__ void put16(U16* base, int row, int col, U16 v) {
    int slot = (col >> 3) ^ (row & SW);
    base[row * RS + slot * 8 + (col & 7)] = v;
}
template <int RS, int SW>
__device__ __forceinline__ void put64(U16* base, int row, int col0,
                                      U16 v0, U16 v1, U16 v2, U16 v3) {
    int slot = (col0 >> 3) ^ (row & SW);
    U32* p = (U32*)(base + row * RS + slot * 8 + (col0 & 7));
    p[0] = (U32)v0 | ((U32)v1 << 16);
    p[1] = (U32)v2 | ((U32)v3 << 16);
}

// stage 8 consecutive elements (cols c8*8..+7) of one row into hi/lo planes
__device__ __forceinline__ void stage8(U16* ph, U16* pl, int row, int c8,
                                       float4 a, float4 b) {
    U16 h[8], l[8];
    split_hl(a.x, h[0], l[0]); split_hl(a.y, h[1], l[1]);
    split_hl(a.z, h[2], l[2]); split_hl(a.w, h[3], l[3]);
    split_hl(b.x, h[4], l[4]); split_hl(b.y, h[5], l[5]);
    split_hl(b.z, h[6], l[6]); split_hl(b.w, h[7], l[7]);
    u32x4 hv, lv;
    #pragma unroll
    for (int q = 0; q < 4; ++q) {
        hv[q] = (U32)h[2*q] | ((U32)h[2*q+1] << 16);
        lv[q] = (U32)l[2*q] | ((U32)l[2*q+1] << 16);
    }
    const int slot = c8 ^ (row & 7);
    *(u32x4*)(ph + row * 64 + slot * 8) = hv;
    *(u32x4*)(pl + row * 64 + slot * 8) = lv;
}

// fused weight conversion for all 3 levels: grid = 3 * 768 blocks
__global__ __launch_bounds__(256) void convert_w3(
    const float* __restrict__ Wq1, const float* __restrict__ Wo1,
    U16* __restrict__ q1h, U16* __restrict__ q1l, U16* __restrict__ o1h, U16* __restrict__ o1l,
    const float* __restrict__ Wq2, const float* __restrict__ Wo2,
    U16* __restrict__ q2h, U16* __restrict__ q2l, U16* __restrict__ o2h, U16* __restrict__ o2l,
    const float* __restrict__ Wq3, const float* __restrict__ Wo3,
    U16* __restrict__ q3h, U16* __restrict__ q3l, U16* __restrict__ o3h, U16* __restrict__ o3l)
{
    int set = blockIdx.x / 768;
    int i = (blockIdx.x % 768) * 256 + threadIdx.x;
    const float* Wq = (set == 0) ? Wq1 : (set == 1) ? Wq2 : Wq3;
    const float* Wo = (set == 0) ? Wo1 : (set == 1) ? Wo2 : Wo3;
    U16* qh = (set == 0) ? q1h : (set == 1) ? q2h : q3h;
    U16* ql = (set == 0) ? q1l : (set == 1) ? q2l : q3l;
    U16* oh = (set == 0) ? o1h : (set == 1) ? o2h : o3h;
    U16* ol = (set == 0) ? o1l : (set == 1) ? o2l : o3l;
    if (i < 768 * 256) { U16 h, l; split_hl(Wq[i], h, l); qh[i] = h; ql[i] = l; }
    if (i < 256 * 256) { U16 h, l; split_hl(Wo[i], h, l); oh[i] = h; ol[i] = l; }
}

// ---- word level: 1 block = 1 sequence (L=64), 256 threads = 4 waves ----
__global__ __launch_bounds__(256, 2) void word_mfma(
    const float* __restrict__ x, const int* __restrict__ am,
    const U16* __restrict__ Wqh, const U16* __restrict__ Wql,
    const float* __restrict__ bqkv,
    const float* __restrict__ Wo32,   // fp32 [256][256]
    const float* __restrict__ bo,
    U16* __restrict__ sent_hi, U16* __restrict__ sent_lo,
    float* __restrict__ smask)
{
    __shared__ __align__(16) U16 QsH[64 * 64], QsL[64 * 64];  // Q, later P
    __shared__ __align__(16) U16 KsH[64 * 64], KsL[64 * 64];  // K; end: scratch
    __shared__ __align__(16) U16 VXH[64 * 64], VXL[64 * 64];  // x chunk / V^T
    __shared__ float msk[64];
    __shared__ float smsum;

    const int t = threadIdx.x;
    const int w = t >> 6, l = t & 63, l15 = l & 15, lhi = l >> 4;
    const int b = blockIdx.x;
    const float* xb = x + (size_t)b * 16384;

    if (t < 64) msk[t] = (float)am[b * 64 + t];

    const int r0 = t >> 3, c8 = t & 7;
    const int r1 = r0 + 32;

    float po[16];   // pooled-O partials, static-indexed only (uniform h branch)

    #pragma unroll 1
    for (int h = 0; h < 4; ++h) {
        // ---------------- QKV over 4 k-chunks of 64 (VX planes = x chunk) ------
        float4 s00 = *(const float4*)(xb + r0 * 256 + c8 * 8);
        float4 s01 = *(const float4*)(xb + r0 * 256 + c8 * 8 + 4);
        float4 s10 = *(const float4*)(xb + r1 * 256 + c8 * 8);
        float4 s11 = *(const float4*)(xb + r1 * 256 + c8 * 8 + 4);
        f32x4 acc[3][4];
        #pragma unroll
        for (int j = 0; j < 3; ++j)
            #pragma unroll
            for (int mt = 0; mt < 4; ++mt) acc[j][mt] = f32x4{0.f, 0.f, 0.f, 0.f};

        for (int kc = 0; kc < 4; ++kc) {
            __syncthreads();                    // VX writable (prev readers done)
            stage8(VXH, VXL, r0, c8, s00, s01);
            stage8(VXH, VXL, r1, c8, s10, s11);
            __syncthreads();                    // VX readable
            if (kc < 3) {                       // prefetch next chunk (T14)
                s00 = *(const float4*)(xb + r0 * 256 + (kc + 1) * 64 + c8 * 8);
                s01 = *(const float4*)(xb + r0 * 256 + (kc + 1) * 64 + c8 * 8 + 4);
                s10 = *(const float4*)(xb + r1 * 256 + (kc + 1) * 64 + c8 * 8);
                s11 = *(const float4*)(xb + r1 * 256 + (kc + 1) * 64 + c8 * 8 + 4);
            }
            #pragma unroll
            for (int ks = 0; ks < 2; ++ks) {
                const int kt = ks * 32;              // k within 64-wide tile
                const int kk = kc * 64 + kt + lhi * 8;
                const size_t wr0 = (size_t)(          h * 64 + w * 16 + l15) * 256 + kk;
                const size_t wr1 = (size_t)(256     + h * 64 + w * 16 + l15) * 256 + kk;
                const size_t wr2 = (size_t)(512     + h * 64 + w * 16 + l15) * 256 + kk;
                u32x4 wh0 = *(const u32x4*)(Wqh + wr0);
                u32x4 wl0 = *(const u32x4*)(Wql + wr0);
                u32x4 wh1 = *(const u32x4*)(Wqh + wr1);
                u32x4 wl1 = *(const u32x4*)(Wql + wr1);
                u32x4 wh2 = *(const u32x4*)(Wqh + wr2);
                u32x4 wl2 = *(const u32x4*)(Wql + wr2);
                #pragma unroll
                for (int mt = 0; mt < 4; ++mt) {
                    u32x4 xh = fragp<64, 7>(VXH, mt * 16 + l15, kt, lhi);
                    u32x4 xl = fragp<64, 7>(VXL, mt * 16 + l15, kt, lhi);
                    acc[0][mt] = MFMA(xh, wh0, acc[0][mt]);
                    acc[0][mt] = MFMA(xh, wl0, acc[0][mt]);
                    acc[0][mt] = MFMA(xl, wh0, acc[0][mt]);
                    acc[1][mt] = MFMA(xh, wh1, acc[1][mt]);
                    acc[1][mt] = MFMA(xh, wl1, acc[1][mt]);
                    acc[1][mt] = MFMA(xl, wh1, acc[1][mt]);
                    acc[2][mt] = MFMA(xh, wh2, acc[2][mt]);
                    acc[2][mt] = MFMA(xh, wl2, acc[2][mt]);
                    acc[2][mt] = MFMA(xl, wh2, acc[2][mt]);
                }
            }
        }
        // ---- write Q / K planes (no VX conflict, before the barrier) ----
        {
            const float bQ = bqkv[      h * 64 + w * 16 + l15];
            const float bK = bqkv[256 + h * 64 + w * 16 + l15];
            #pragma unroll
            for (int mt = 0; mt < 4; ++mt) {
                #pragma unroll
                for (int r = 0; r < 4; ++r) {
                    U16 vH, vL;
                    split_hl(acc[0][mt][r] + bQ, vH, vL);
                    put16<64, 7>(QsH, mt * 16 + lhi * 4 + r, w * 16 + l15, vH);
                    put16<64, 7>(QsL, mt * 16 + lhi * 4 + r, w * 16 + l15, vL);
                    split_hl(acc[1][mt][r] + bK, vH, vL);
                    put16<64, 7>(KsH, mt * 16 + lhi * 4 + r, w * 16 + l15, vH);
                    put16<64, 7>(KsL, mt * 16 + lhi * 4 + r, w * 16 + l15, vL);
                }
            }
        }
        __syncthreads();   // all chunk-3 VX reads done -> V^T may overwrite VX
        {
            const float bV = bqkv[512 + h * 64 + w * 16 + l15];
            const int d = w * 16 + l15;
            #pragma unroll
            for (int mt = 0; mt < 4; ++mt) {
                U16 h4[4], l4[4];
                #pragma unroll
                for (int r = 0; r < 4; ++r)
                    split_hl(acc[2][mt][r] + bV, h4[r], l4[r]);
                put64<64, 7>(VXH, d, mt * 16 + lhi * 4, h4[0], h4[1], h4[2], h4[3]);
                put64<64, 7>(VXL, d, mt * 16 + lhi * 4, l4[0], l4[1], l4[2], l4[3]);
            }
        }
        __syncthreads();   // Q, K, V^T ready
        if (h == 0 && t == 0) {
            float s = 0.f;
            for (int i = 0; i < 64; ++i) s += msk[i];
            smsum = s;
        }

        // ------- scores + softmax + P (wave w owns row-tile w) -------
        {
            f32x4 sa[4];
            #pragma unroll
            for (int i = 0; i < 4; ++i) sa[i] = f32x4{0.f, 0.f, 0.f, 0.f};
            #pragma unroll
            for (int ks = 0; ks < 2; ++ks) {
                const int kt = ks * 32;
                u32x4 qh = fragp<64, 7>(QsH, w * 16 + l15, kt, lhi);
                u32x4 ql = fragp<64, 7>(QsL, w * 16 + l15, kt, lhi);
                #pragma unroll
                for (int nt = 0; nt < 4; ++nt) {
                    u32x4 kh = fragp<64, 7>(KsH, nt * 16 + l15, kt, lhi);
                    u32x4 kl = fragp<64, 7>(KsL, nt * 16 + l15, kt, lhi);
                    sa[nt] = MFMA(qh, kh, sa[nt]);
                    sa[nt] = MFMA(qh, kl, sa[nt]);
                    sa[nt] = MFMA(ql, kh, sa[nt]);
                }
            }
            float sc[4][4];
            #pragma unroll
            for (int nt = 0; nt < 4; ++nt) {
                const float mterm = (1.0f - msk[nt * 16 + l15]) * -1e9f;
                #pragma unroll
                for (int r = 0; r < 4; ++r) sc[nt][r] = sa[nt][r] * 0.125f + mterm;
            }
            #pragma unroll
            for (int r = 0; r < 4; ++r) {
                float m = fmaxf(fmaxf(sc[0][r], sc[1][r]), fmaxf(sc[2][r], sc[3][r]));
                #pragma unroll
                for (int off = 1; off < 16; off <<= 1) m = fmaxf(m, __shfl_xor(m, off));
                float e0 = expf(sc[0][r] - m), e1 = expf(sc[1][r] - m);
                float e2 = expf(sc[2][r] - m), e3 = expf(sc[3][r] - m);
                float s = e0 + e1 + e2 + e3;
                #pragma unroll
                for (int off = 1; off < 16; off <<= 1) s += __shfl_xor(s, off);
                const float inv = 1.0f / s;
                sc[0][r] = e0 * inv; sc[1][r] = e1 * inv;
                sc[2][r] = e2 * inv; sc[3][r] = e3 * inv;
            }
            #pragma unroll
            for (int nt = 0; nt < 4; ++nt) {
                #pragma unroll
                for (int r = 0; r < 4; ++r) {
                    U16 vH, vL; split_hl(sc[nt][r], vH, vL);
                    put16<64, 7>(QsH, w * 16 + lhi * 4 + r, nt * 16 + l15, vH);
                    put16<64, 7>(QsL, w * 16 + lhi * 4 + r, nt * 16 + l15, vL);
                }
            }
        }
        // ------- PV (P own rows; V^T barriered) + masked row-sum -------
        {
            f32x4 pa[4];
            #pragma unroll
            for (int i = 0; i < 4; ++i) pa[i] = f32x4{0.f, 0.f, 0.f, 0.f};
            #pragma unroll
            for (int ks = 0; ks < 2; ++ks) {
                const int kt = ks * 32;
                u32x4 ph = fragp<64, 7>(QsH, w * 16 + l15, kt, lhi);
                u32x4 pl = fragp<64, 7>(QsL, w * 16 + l15, kt, lhi);
                #pragma unroll
                for (int nt = 0; nt < 4; ++nt) {
                    u32x4 vh = fragp<64, 7>(VXH, nt * 16 + l15, kt, lhi);
                    u32x4 vl = fragp<64, 7>(VXL, nt * 16 + l15, kt, lhi);
                    pa[nt] = MFMA(ph, vh, pa[nt]);
                    pa[nt] = MFMA(ph, vl, pa[nt]);
                    pa[nt] = MFMA(pl, vh, pa[nt]);
                }
            }
            float sarr[4];
            #pragma unroll
            for (int nt = 0; nt < 4; ++nt) {
                float s = 0.f;
                #pragma unroll
                for (int r = 0; r < 4; ++r)
                    s += msk[w * 16 + lhi * 4 + r] * pa[nt][r];
                s += __shfl_xor(s, 16);
                s += __shfl_xor(s, 32);
                sarr[nt] = s;
            }
            // static po indices via uniform branch on h (rule #20)
            if (h == 0) {
                po[0] = sarr[0]; po[1] = sarr[1]; po[2] = sarr[2]; po[3] = sarr[3];
            } else if (h == 1) {
                po[4] = sarr[0]; po[5] = sarr[1]; po[6] = sarr[2]; po[7] = sarr[3];
            } else if (h == 2) {
                po[8] = sarr[0]; po[9] = sarr[1]; po[10] = sarr[2]; po[11] = sarr[3];
            } else {
                po[12] = sarr[0]; po[13] = sarr[1]; po[14] = sarr[2]; po[15] = sarr[3];
            }
        }
        // next head's kc=0 top barrier orders all VX/Qs/Ks rewrites after reads
    }

    // ---------------- epilogue: cross-wave pool sum + fp32 out-proj ----------------
    __syncthreads();   // all waves done h=3 scores/PV; Ks region free
    float (*part)[256] = (float(*)[256])KsH;   // 4 KB into the 8 KB plane
    if (lhi == 0) {
        #pragma unroll
        for (int hh = 0; hh < 4; ++hh)
            #pragma unroll
            for (int nt = 0; nt < 4; ++nt)
                part[w][hh * 64 + nt * 16 + l15] = po[hh * 4 + nt];
    }
    __syncthreads();
    {
        float opv = part[0][t] + part[1][t] + part[2][t] + part[3][t];
        part[0][t] = opv;   // own index; becomes the broadcast buffer
    }
    __syncthreads();
    {
        const float* wrow = Wo32 + (size_t)t * 256;
        const float* opool = part[0];
        float s = 0.f;
        #pragma unroll 8
        for (int c = 0; c < 256; c += 4) {
            float4 wv = *(const float4*)(wrow + c);
            s += opool[c] * wv.x + opool[c + 1] * wv.y
               + opool[c + 2] * wv.z + opool[c + 3] * wv.w;
        }
        float m = smsum;
        float val = (s + bo[t] * m) / (m + 1e-10f);
        U16 vH, vL; split_hl(val, vH, vL);
        sent_hi[(size_t)b * 256 + t] = vH;
        sent_lo[(size_t)b * 256 + t] = vL;
    }
    if (t == 0) smask[b] = (smsum > 0.f) ? 1.f : 0.f;
}

// ---- levels 2/3: L in {16, 8}; unchanged (passes, ~30 us total) ----
template <int L>
__global__ __launch_bounds__(256) void mha_small(
    const U16* __restrict__ xh, const U16* __restrict__ xl,
    const float* __restrict__ mk,
    const U16* __restrict__ Wqh, const U16* __restrict__ Wql,
    const float* __restrict__ bqkv,
    const U16* __restrict__ Woh, const U16* __restrict__ Wol,
    const float* __restrict__ bo,
    float* __restrict__ out_f32, U16* __restrict__ out_hi, U16* __restrict__ out_lo,
    float* __restrict__ outmask)
{
    __shared__ __align__(16) U16 xs_h[16*256], xs_l[16*256];
    __shared__ __align__(16) U16 Qh_[16*256], Ql_[16*256];
    __shared__ __align__(16) U16 Kh_[16*256], Kl_[16*256];
    __shared__ __align__(16) U16 Vh_[256*32], Vl_[256*32];
    __shared__ __align__(16) U16 Ph_[4][16*32], Pl_[4][16*32];
    __shared__ __align__(16) U16 Oh_[16*256], Ol_[16*256];
    __shared__ float msk[16];
    __shared__ float smsum;

    const int t = threadIdx.x;
    const int w = t >> 6, l = t & 63, l15 = l & 15, lhi = l >> 4;
    const int b = blockIdx.x;

    if (t < 16) msk[t] = (t < L) ? mk[b*L + t] : 0.f;

    #pragma unroll
    for (int i = 0; i < 2; ++i) {
        int c = i*256 + t;
        int row = c >> 5, c8 = c & 31;
        u32x4 hv = u32x4{0,0,0,0}, lv = u32x4{0,0,0,0};
        if (row < L) {
            hv = *(const u32x4*)(xh + ((size_t)b*L + row)*256 + c8*8);
            lv = *(const u32x4*)(xl + ((size_t)b*L + row)*256 + c8*8);
        }
        int slot = c8 ^ (row & 7);
        *(u32x4*)(xs_h + row*256 + slot*8) = hv;
        *(u32x4*)(xs_l + row*256 + slot*8) = lv;
    }
    #pragma unroll
    for (int i = 0; i < 4; ++i) {
        int c = i*256 + t;
        *(u32x4*)(Vh_ + c*8) = u32x4{0,0,0,0};
        *(u32x4*)(Vl_ + c*8) = u32x4{0,0,0,0};
    }
    *(u32x4*)(&Ph_[0][0] + t*8) = u32x4{0,0,0,0};
    *(u32x4*)(&Pl_[0][0] + t*8) = u32x4{0,0,0,0};
    __syncthreads();
    if (t == 0) { float s = 0.f; for (int i = 0; i < 16; ++i) s += msk[i]; smsum = s; }

    {
        f32x4 acc[12];
        #pragma unroll
        for (int i = 0; i < 12; ++i) acc[i] = f32x4{0.f,0.f,0.f,0.f};
        #pragma unroll 2
        for (int k0 = 0; k0 < 256; k0 += 32) {
            u32x4 ah = fragp<256,7>(xs_h, l15, k0, lhi);
            u32x4 al = fragp<256,7>(xs_l, l15, k0, lhi);
            #pragma unroll
            for (int j = 0; j < 12; ++j) {
                int u = w*12 + j;
                u32x4 wh = *(const u32x4*)(Wqh + (size_t)(u*16 + l15)*256 + k0 + lhi*8);
                u32x4 wl = *(const u32x4*)(Wql + (size_t)(u*16 + l15)*256 + k0 + lhi*8);
                acc[j] = MFMA(ah, wh, acc[j]);
                acc[j] = MFMA(ah, wl, acc[j]);
                acc[j] = MFMA(al, wh, acc[j]);
            }
        }
        #pragma unroll
        for (int j = 0; j < 12; ++j) {
            int u = w*12 + j;
            int mat = u >> 4, cg = u & 15;
            float bias = bqkv[u*16 + l15];
            if (mat < 2) {
                U16* dh = (mat == 0) ? Qh_ : Kh_;
                U16* dl = (mat == 0) ? Ql_ : Kl_;
                #pragma unroll
                for (int r = 0; r < 4; ++r) {
                    U16 vH, vL; split_hl(acc[j][r] + bias, vH, vL);
                    put16<256,7>(dh, lhi*4 + r, cg*16 + l15, vH);
                    put16<256,7>(dl, lhi*4 + r, cg*16 + l15, vL);
                }
            } else {
                U16 h4[4], l4[4];
                #pragma unroll
                for (int r = 0; r < 4; ++r) split_hl(acc[j][r] + bias, h4[r], l4[r]);
                put64<32,3>(Vh_, cg*16 + l15, lhi*4, h4[0],h4[1],h4[2],h4[3]);
                put64<32,3>(Vl_, cg*16 + l15, lhi*4, l4[0],l4[1],l4[2],l4[3]);
            }
        }
    }
    __syncthreads();

    {
        const int h = w;
        f32x4 sa = f32x4{0.f,0.f,0.f,0.f};
        #pragma unroll
        for (int k0 = 0; k0 < 64; k0 += 32) {
            u32x4 qh = fragp<256,7>(Qh_, l15, h*64 + k0, lhi);
            u32x4 ql = fragp<256,7>(Ql_, l15, h*64 + k0, lhi);
            u32x4 kh = fragp<256,7>(Kh_, l15, h*64 + k0, lhi);
            u32x4 kl = fragp<256,7>(Kl_, l15, h*64 + k0, lhi);
            sa = MFMA(qh, kh, sa);
            sa = MFMA(qh, kl, sa);
            sa = MFMA(ql, kh, sa);
        }
        float sc[4];
        float mterm = (1.0f - msk[l15]) * -1e9f;
        #pragma unroll
        for (int r = 0; r < 4; ++r) sc[r] = sa[r] * 0.125f + mterm;
        #pragma unroll
        for (int r = 0; r < 4; ++r) {
            float m = sc[r];
            #pragma unroll
            for (int off = 1; off < 16; off <<= 1) m = fmaxf(m, __shfl_xor(m, off));
            float e = expf(sc[r] - m);
            float s = e;
            #pragma unroll
            for (int off = 1; off < 16; off <<= 1) s += __shfl_xor(s, off);
            sc[r] = e / s;
        }
        #pragma unroll
        for (int r = 0; r < 4; ++r) {
            U16 vH, vL; split_hl(sc[r], vH, vL);
            put16<32,3>(&Ph_[h][0], lhi*4 + r, l15, vH);
            put16<32,3>(&Pl_[h][0], lhi*4 + r, l15, vL);
        }
        f32x4 pa[4];
        #pragma unroll
        for (int i = 0; i < 4; ++i) pa[i] = f32x4{0.f,0.f,0.f,0.f};
        {
            u32x4 ph = fragp<32,3>(&Ph_[h][0], l15, 0, lhi);
            u32x4 pl = fragp<32,3>(&Pl_[h][0], l15, 0, lhi);
            #pragma unroll
            for (int ntl = 0; ntl < 4; ++ntl) {
                u32x4 vh = fragp<32,3>(Vh_, h*64 + ntl*16 + l15, 0, lhi);
                u32x4 vl = fragp<32,3>(Vl_, h*64 + ntl*16 + l15, 0, lhi);
                pa[ntl] = MFMA(ph, vh, pa[ntl]);
                pa[ntl] = MFMA(ph, vl, pa[ntl]);
                pa[ntl] = MFMA(pl, vh, pa[ntl]);
            }
        }
        #pragma unroll
        for (int ntl = 0; ntl < 4; ++ntl) {
            #pragma unroll
            for (int r = 0; r < 4; ++r) {
                U16 vH, vL; split_hl(pa[ntl][r], vH, vL);
                put16<256,7>(Oh_, lhi*4 + r, h*64 + ntl*16 + l15, vH);
                put16<256,7>(Ol_, lhi*4 + r, h*64 + ntl*16 + l15, vL);
            }
        }
    }
    __syncthreads();

    {
        f32x4 acc4[4];
        #pragma unroll
        for (int i = 0; i < 4; ++i) acc4[i] = f32x4{0.f,0.f,0.f,0.f};
        #pragma unroll 2
        for (int k0 = 0; k0 < 256; k0 += 32) {
            u32x4 oh = fragp<256,7>(Oh_, l15, k0, lhi);
            u32x4 ol = fragp<256,7>(Ol_, l15, k0, lhi);
            #pragma unroll
            for (int j = 0; j < 4; ++j) {
                int oc = w*64 + j*16 + l15;
                u32x4 wh = *(const u32x4*)(Woh + (size_t)oc*256 + k0 + lhi*8);
                u32x4 wl = *(const u32x4*)(Wol + (size_t)oc*256 + k0 + lhi*8);
                acc4[j] = MFMA(oh, wh, acc4[j]);
                acc4[j] = MFMA(oh, wl, acc4[j]);
                acc4[j] = MFMA(ol, wh, acc4[j]);
            }
        }
        float msum = smsum;
        #pragma unroll
        for (int j = 0; j < 4; ++j) {
            float s = 0.f;
            #pragma unroll
            for (int r = 0; r < 4; ++r) s += msk[lhi*4 + r] * acc4[j][r];
            s += __shfl_xor(s, 16);
            s += __shfl_xor(s, 32);
            if (lhi == 0) {
                int col = w*64 + j*16 + l15;
                float val = (s + bo[col] * msum) / (msum + 1e-10f);
                if (out_f32) out_f32[(size_t)b*256 + col] = val;
                if (out_hi) {
                    U16 vH, vL; split_hl(val, vH, vL);
                    out_hi[(size_t)b*256 + col] = vH;
                    out_lo[(size_t)b*256 + col] = vL;
                }
            }
        }
    }
    if (t == 0 && outmask) outmask[b] = (smsum > 0.f) ? 1.f : 0.f;
}

extern "C" void kernel_launch(void* const* d_in, const int* in_sizes, int n_in,
                              void* d_out, int out_size, void* d_ws, size_t ws_size,
                              hipStream_t stream) {
    (void)in_sizes; (void)n_in; (void)out_size; (void)ws_size;
    const float* we  = (const float*)d_in[0];
    const int*   am  = (const int*)d_in[1];
    const float* wW  = (const float*)d_in[2];
    const float* wb  = (const float*)d_in[3];
    const float* wO  = (const float*)d_in[4];
    const float* wob = (const float*)d_in[5];
    const float* sW  = (const float*)d_in[6];
    const float* sb  = (const float*)d_in[7];
    const float* sO  = (const float*)d_in[8];
    const float* sob = (const float*)d_in[9];
    const float* cW  = (const float*)d_in[10];
    const float* cb  = (const float*)d_in[11];
    const float* cO  = (const float*)d_in[12];
    const float* cob = (const float*)d_in[13];

    U16* p = (U16*)d_ws;
    U16* sent_hi = p; p += 2048*256;
    U16* sent_lo = p; p += 2048*256;
    U16* sect_hi = p; p += 128*256;
    U16* sect_lo = p; p += 128*256;
    U16* w1qh = p; p += 768*256;  U16* w1ql = p; p += 768*256;
    U16* w1oh = p; p += 256*256;  U16* w1ol = p; p += 256*256;
    U16* w2qh = p; p += 768*256;  U16* w2ql = p; p += 768*256;
    U16* w2oh = p; p += 256*256;  U16* w2ol = p; p += 256*256;
    U16* w3qh = p; p += 768*256;  U16* w3ql = p; p += 768*256;
    U16* w3oh = p; p += 256*256;  U16* w3ol = p; p += 256*256;
    float* smaskb = (float*)p;
    float* cmaskb = smaskb + 2048;

    convert_w3<<<3 * 768, 256, 0, stream>>>(
        wW, wO, w1qh, w1ql, w1oh, w1ol,
        sW, sO, w2qh, w2ql, w2oh, w2ol,
        cW, cO, w3qh, w3ql, w3oh, w3ol);
    word_mfma<<<2048, 256, 0, stream>>>(we, am, w1qh, w1ql, wb, wO, wob,
                                        sent_hi, sent_lo, smaskb);
    mha_small<16><<<128, 256, 0, stream>>>(sent_hi, sent_lo, smaskb,
                                           w2qh, w2ql, sb, w2oh, w2ol, sob,
                                           nullptr, sect_hi, sect_lo, cmaskb);
    mha_small<8><<<16, 256, 0, stream>>>(sect_hi, sect_lo, cmaskb,
                                         w3qh, w3ql, cb, w3oh, w3ol, cob,
                                         (float*)d_out, nullptr, nullptr, nullptr);
}

// Round 20
// 381.825 us; speedup vs baseline: 1.4269x; 1.0698x over previous
//
#include <hip/hip_runtime.h>
#include <hip/hip_bf16.h>

// Hierarchical attention, 3 levels. Split-bf16 MFMA; out-proj commuted with
// masked mean pool (exact fp32 matvec epilogue).
// r20 = r19 with QKV A-operand single-bf16 (drop x_lo x W_hi correction):
//   QKV per-tile MFMAs 3 -> 2 (-29% total MFMA work), x staging packs hi
//   plane only (staging VALU ~halved), QKV ds_reads halved.
// Precision analysis: x_lo/x ~ 2^-9 -> Q/K/V rel err ~1e-3; independent per
// row -> pooled down ~sqrt(32); through exact-fp32 out-proj + 2 near-exact
// levels -> predicted final absmax ~1-2e-5 vs 5.1e-5 threshold.
// Attention path (scores/PV) keeps FULL hi/lo split (Q,K,P,V).
// W stays split (x_hi*W_hi + x_hi*W_lo). Structure identical to r19/r16.

typedef short bf16x8 __attribute__((ext_vector_type(8)));
typedef float f32x4 __attribute__((ext_vector_type(4)));
typedef unsigned int u32x4 __attribute__((ext_vector_type(4)));
typedef unsigned short U16;
typedef unsigned int U32;

__device__ __forceinline__ U16 f2bf(float f) {
    __hip_bfloat16 b = __float2bfloat16(f);   // HW cvt (RNE)
    return __builtin_bit_cast(U16, b);
}
__device__ __forceinline__ void split_hl(float f, U16& h, U16& l) {
    h = f2bf(f);
    float hf = __builtin_bit_cast(float, (U32)h << 16);
    l = f2bf(f - hf);
}

#define MFMA(A, B, C) __builtin_amdgcn_mfma_f32_16x16x32_bf16( \
    __builtin_bit_cast(bf16x8, A), __builtin_bit_cast(bf16x8, B), C, 0, 0, 0)

// u16 plane helpers. RS = row stride (u16 units), SW = row swizzle mask.
// Element k of row r lives at 16B-slot ((k>>3) ^ (r & SW)).
template <int RS, int SW>
__device__ __forceinline__ u32x4 fragp(const U16* base, int row, int k, int lhi) {
    int slot = ((k >> 3) + lhi) ^ (row & SW);
    return *(const u32x4*)(base + row * RS + slot * 8);
}
template <int RS, int SW>
__device__ __forceinline__ void put16(U16* base, int row, int col, U16 v) {
    int slot = (col >> 3) ^ (row & SW);
    base[row * RS + slot * 8 + (col & 7)] = v;
}
template <int RS, int SW>
__device__ __forceinline__ void put64(U16* base, int row, int col0,
                                      U16 v0, U16 v1, U16 v2, U16 v3) {
    int slot = (col0 >> 3) ^ (row & SW);
    U32* p = (U32*)(base + row * RS + slot * 8 + (col0 & 7));
    p[0] = (U32)v0 | ((U32)v1 << 16);
    p[1] = (U32)v2 | ((U32)v3 << 16);
}

// stage 8 consecutive elements of one row into the HI plane only (QKV A-op
// is single-bf16; no lo plane needed for x)
__device__ __forceinline__ void stage8h(U16* ph, int row, int c8,
                                        float4 a, float4 b) {
    U16 h[8];
    h[0] = f2bf(a.x); h[1] = f2bf(a.y); h[2] = f2bf(a.z); h[3] = f2bf(a.w);
    h[4] = f2bf(b.x); h[5] = f2bf(b.y); h[6] = f2bf(b.z); h[7] = f2bf(b.w);
    u32x4 hv;
    #pragma unroll
    for (int q = 0; q < 4; ++q)
        hv[q] = (U32)h[2*q] | ((U32)h[2*q+1] << 16);
    const int slot = c8 ^ (row & 7);
    *(u32x4*)(ph + row * 64 + slot * 8) = hv;
}

// fused weight conversion for all 3 levels: grid = 3 * 768 blocks
__global__ __launch_bounds__(256) void convert_w3(
    const float* __restrict__ Wq1, const float* __restrict__ Wo1,
    U16* __restrict__ q1h, U16* __restrict__ q1l, U16* __restrict__ o1h, U16* __restrict__ o1l,
    const float* __restrict__ Wq2, const float* __restrict__ Wo2,
    U16* __restrict__ q2h, U16* __restrict__ q2l, U16* __restrict__ o2h, U16* __restrict__ o2l,
    const float* __restrict__ Wq3, const float* __restrict__ Wo3,
    U16* __restrict__ q3h, U16* __restrict__ q3l, U16* __restrict__ o3h, U16* __restrict__ o3l)
{
    int set = blockIdx.x / 768;
    int i = (blockIdx.x % 768) * 256 + threadIdx.x;
    const float* Wq = (set == 0) ? Wq1 : (set == 1) ? Wq2 : Wq3;
    const float* Wo = (set == 0) ? Wo1 : (set == 1) ? Wo2 : Wo3;
    U16* qh = (set == 0) ? q1h : (set == 1) ? q2h : q3h;
    U16* ql = (set == 0) ? q1l : (set == 1) ? q2l : q3l;
    U16* oh = (set == 0) ? o1h : (set == 1) ? o2h : o3h;
    U16* ol = (set == 0) ? o1l : (set == 1) ? o2l : o3l;
    if (i < 768 * 256) { U16 h, l; split_hl(Wq[i], h, l); qh[i] = h; ql[i] = l; }
    if (i < 256 * 256) { U16 h, l; split_hl(Wo[i], h, l); oh[i] = h; ol[i] = l; }
}

// ---- word level: 1 block = 1 sequence (L=64), 256 threads = 4 waves ----
__global__ __launch_bounds__(256, 2) void word_mfma(
    const float* __restrict__ x, const int* __restrict__ am,
    const U16* __restrict__ Wqh, const U16* __restrict__ Wql,
    const float* __restrict__ bqkv,
    const float* __restrict__ Wo32,   // fp32 [256][256]
    const float* __restrict__ bo,
    U16* __restrict__ sent_hi, U16* __restrict__ sent_lo,
    float* __restrict__ smask)
{
    __shared__ __align__(16) U16 QsH[64 * 64], QsL[64 * 64];  // Q, later P
    __shared__ __align__(16) U16 KsH[64 * 64], KsL[64 * 64];  // K; end: scratch
    __shared__ __align__(16) U16 VXH[64 * 64], VXL[64 * 64];  // x chunk (hi only) / V^T (hi+lo)
    __shared__ float msk[64];
    __shared__ float smsum;

    const int t = threadIdx.x;
    const int w = t >> 6, l = t & 63, l15 = l & 15, lhi = l >> 4;
    const int b = blockIdx.x;
    const float* xb = x + (size_t)b * 16384;

    if (t < 64) msk[t] = (float)am[b * 64 + t];

    const int r0 = t >> 3, c8 = t & 7;
    const int r1 = r0 + 32;

    float po[16];   // pooled-O partials, static-indexed only (uniform h branch)

    #pragma unroll 1
    for (int h = 0; h < 4; ++h) {
        // ---------------- QKV over 4 k-chunks of 64 (VXH = x chunk, hi only) ----
        float4 s00 = *(const float4*)(xb + r0 * 256 + c8 * 8);
        float4 s01 = *(const float4*)(xb + r0 * 256 + c8 * 8 + 4);
        float4 s10 = *(const float4*)(xb + r1 * 256 + c8 * 8);
        float4 s11 = *(const float4*)(xb + r1 * 256 + c8 * 8 + 4);
        f32x4 acc[3][4];
        #pragma unroll
        for (int j = 0; j < 3; ++j)
            #pragma unroll
            for (int mt = 0; mt < 4; ++mt) acc[j][mt] = f32x4{0.f, 0.f, 0.f, 0.f};

        for (int kc = 0; kc < 4; ++kc) {
            __syncthreads();                    // VX writable (prev readers done)
            stage8h(VXH, r0, c8, s00, s01);
            stage8h(VXH, r1, c8, s10, s11);
            __syncthreads();                    // VX readable
            if (kc < 3) {                       // prefetch next chunk (T14)
                s00 = *(const float4*)(xb + r0 * 256 + (kc + 1) * 64 + c8 * 8);
                s01 = *(const float4*)(xb + r0 * 256 + (kc + 1) * 64 + c8 * 8 + 4);
                s10 = *(const float4*)(xb + r1 * 256 + (kc + 1) * 64 + c8 * 8);
                s11 = *(const float4*)(xb + r1 * 256 + (kc + 1) * 64 + c8 * 8 + 4);
            }
            #pragma unroll
            for (int ks = 0; ks < 2; ++ks) {
                const int kt = ks * 32;              // k within 64-wide tile
                const int kk = kc * 64 + kt + lhi * 8;
                const size_t wr0 = (size_t)(          h * 64 + w * 16 + l15) * 256 + kk;
                const size_t wr1 = (size_t)(256     + h * 64 + w * 16 + l15) * 256 + kk;
                const size_t wr2 = (size_t)(512     + h * 64 + w * 16 + l15) * 256 + kk;
                u32x4 wh0 = *(const u32x4*)(Wqh + wr0);
                u32x4 wl0 = *(const u32x4*)(Wql + wr0);
                u32x4 wh1 = *(const u32x4*)(Wqh + wr1);
                u32x4 wl1 = *(const u32x4*)(Wql + wr1);
                u32x4 wh2 = *(const u32x4*)(Wqh + wr2);
                u32x4 wl2 = *(const u32x4*)(Wql + wr2);
                #pragma unroll
                for (int mt = 0; mt < 4; ++mt) {
                    u32x4 xh = fragp<64, 7>(VXH, mt * 16 + l15, kt, lhi);
                    acc[0][mt] = MFMA(xh, wh0, acc[0][mt]);
                    acc[0][mt] = MFMA(xh, wl0, acc[0][mt]);
                    acc[1][mt] = MFMA(xh, wh1, acc[1][mt]);
                    acc[1][mt] = MFMA(xh, wl1, acc[1][mt]);
                    acc[2][mt] = MFMA(xh, wh2, acc[2][mt]);
                    acc[2][mt] = MFMA(xh, wl2, acc[2][mt]);
                }
            }
        }
        // ---- write Q / K planes (no VX conflict, before the barrier) ----
        {
            const float bQ = bqkv[      h * 64 + w * 16 + l15];
            const float bK = bqkv[256 + h * 64 + w * 16 + l15];
            #pragma unroll
            for (int mt = 0; mt < 4; ++mt) {
                #pragma unroll
                for (int r = 0; r < 4; ++r) {
                    U16 vH, vL;
                    split_hl(acc[0][mt][r] + bQ, vH, vL);
                    put16<64, 7>(QsH, mt * 16 + lhi * 4 + r, w * 16 + l15, vH);
                    put16<64, 7>(QsL, mt * 16 + lhi * 4 + r, w * 16 + l15, vL);
                    split_hl(acc[1][mt][r] + bK, vH, vL);
                    put16<64, 7>(KsH, mt * 16 + lhi * 4 + r, w * 16 + l15, vH);
                    put16<64, 7>(KsL, mt * 16 + lhi * 4 + r, w * 16 + l15, vL);
                }
            }
        }
        __syncthreads();   // all chunk-3 VX reads done -> V^T may overwrite VX
        {
            const float bV = bqkv[512 + h * 64 + w * 16 + l15];
            const int d = w * 16 + l15;
            #pragma unroll
            for (int mt = 0; mt < 4; ++mt) {
                U16 h4[4], l4[4];
                #pragma unroll
                for (int r = 0; r < 4; ++r)
                    split_hl(acc[2][mt][r] + bV, h4[r], l4[r]);
                put64<64, 7>(VXH, d, mt * 16 + lhi * 4, h4[0], h4[1], h4[2], h4[3]);
                put64<64, 7>(VXL, d, mt * 16 + lhi * 4, l4[0], l4[1], l4[2], l4[3]);
            }
        }
        __syncthreads();   // Q, K, V^T ready
        if (h == 0 && t == 0) {
            float s = 0.f;
            for (int i = 0; i < 64; ++i) s += msk[i];
            smsum = s;
        }

        // ------- scores + softmax + P (wave w owns row-tile w; FULL split) -------
        {
            f32x4 sa[4];
            #pragma unroll
            for (int i = 0; i < 4; ++i) sa[i] = f32x4{0.f, 0.f, 0.f, 0.f};
            #pragma unroll
            for (int ks = 0; ks < 2; ++ks) {
                const int kt = ks * 32;
                u32x4 qh = fragp<64, 7>(QsH, w * 16 + l15, kt, lhi);
                u32x4 ql = fragp<64, 7>(QsL, w * 16 + l15, kt, lhi);
                #pragma unroll
                for (int nt = 0; nt < 4; ++nt) {
                    u32x4 kh = fragp<64, 7>(KsH, nt * 16 + l15, kt, lhi);
                    u32x4 kl = fragp<64, 7>(KsL, nt * 16 + l15, kt, lhi);
                    sa[nt] = MFMA(qh, kh, sa[nt]);
                    sa[nt] = MFMA(qh, kl, sa[nt]);
                    sa[nt] = MFMA(ql, kh, sa[nt]);
                }
            }
            float sc[4][4];
            #pragma unroll
            for (int nt = 0; nt < 4; ++nt) {
                const float mterm = (1.0f - msk[nt * 16 + l15]) * -1e9f;
                #pragma unroll
                for (int r = 0; r < 4; ++r) sc[nt][r] = sa[nt][r] * 0.125f + mterm;
            }
            #pragma unroll
            for (int r = 0; r < 4; ++r) {
                float m = fmaxf(fmaxf(sc[0][r], sc[1][r]), fmaxf(sc[2][r], sc[3][r]));
                #pragma unroll
                for (int off = 1; off < 16; off <<= 1) m = fmaxf(m, __shfl_xor(m, off));
                float e0 = expf(sc[0][r] - m), e1 = expf(sc[1][r] - m);
                float e2 = expf(sc[2][r] - m), e3 = expf(sc[3][r] - m);
                float s = e0 + e1 + e2 + e3;
                #pragma unroll
                for (int off = 1; off < 16; off <<= 1) s += __shfl_xor(s, off);
                const float inv = 1.0f / s;
                sc[0][r] = e0 * inv; sc[1][r] = e1 * inv;
                sc[2][r] = e2 * inv; sc[3][r] = e3 * inv;
            }
            #pragma unroll
            for (int nt = 0; nt < 4; ++nt) {
                #pragma unroll
                for (int r = 0; r < 4; ++r) {
                    U16 vH, vL; split_hl(sc[nt][r], vH, vL);
                    put16<64, 7>(QsH, w * 16 + lhi * 4 + r, nt * 16 + l15, vH);
                    put16<64, 7>(QsL, w * 16 + lhi * 4 + r, nt * 16 + l15, vL);
                }
            }
        }
        // ------- PV (P own rows; V^T barriered; FULL split) + masked row-sum -------
        {
            f32x4 pa[4];
            #pragma unroll
            for (int i = 0; i < 4; ++i) pa[i] = f32x4{0.f, 0.f, 0.f, 0.f};
            #pragma unroll
            for (int ks = 0; ks < 2; ++ks) {
                const int kt = ks * 32;
                u32x4 ph = fragp<64, 7>(QsH, w * 16 + l15, kt, lhi);
                u32x4 pl = fragp<64, 7>(QsL, w * 16 + l15, kt, lhi);
                #pragma unroll
                for (int nt = 0; nt < 4; ++nt) {
                    u32x4 vh = fragp<64, 7>(VXH, nt * 16 + l15, kt, lhi);
                    u32x4 vl = fragp<64, 7>(VXL, nt * 16 + l15, kt, lhi);
                    pa[nt] = MFMA(ph, vh, pa[nt]);
                    pa[nt] = MFMA(ph, vl, pa[nt]);
                    pa[nt] = MFMA(pl, vh, pa[nt]);
                }
            }
            float sarr[4];
            #pragma unroll
            for (int nt = 0; nt < 4; ++nt) {
                float s = 0.f;
                #pragma unroll
                for (int r = 0; r < 4; ++r)
                    s += msk[w * 16 + lhi * 4 + r] * pa[nt][r];
                s += __shfl_xor(s, 16);
                s += __shfl_xor(s, 32);
                sarr[nt] = s;
            }
            // static po indices via uniform branch on h (rule #20)
            if (h == 0) {
                po[0] = sarr[0]; po[1] = sarr[1]; po[2] = sarr[2]; po[3] = sarr[3];
            } else if (h == 1) {
                po[4] = sarr[0]; po[5] = sarr[1]; po[6] = sarr[2]; po[7] = sarr[3];
            } else if (h == 2) {
                po[8] = sarr[0]; po[9] = sarr[1]; po[10] = sarr[2]; po[11] = sarr[3];
            } else {
                po[12] = sarr[0]; po[13] = sarr[1]; po[14] = sarr[2]; po[15] = sarr[3];
            }
        }
        // next head's kc=0 top barrier orders all VX/Qs/Ks rewrites after reads
    }

    // ---------------- epilogue: cross-wave pool sum + fp32 out-proj ----------------
    __syncthreads();   // all waves done h=3 scores/PV; Ks region free
    float (*part)[256] = (float(*)[256])KsH;   // 4 KB into the 8 KB plane
    if (lhi == 0) {
        #pragma unroll
        for (int hh = 0; hh < 4; ++hh)
            #pragma unroll
            for (int nt = 0; nt < 4; ++nt)
                part[w][hh * 64 + nt * 16 + l15] = po[hh * 4 + nt];
    }
    __syncthreads();
    {
        float opv = part[0][t] + part[1][t] + part[2][t] + part[3][t];
        part[0][t] = opv;   // own index; becomes the broadcast buffer
    }
    __syncthreads();
    {
        const float* wrow = Wo32 + (size_t)t * 256;
        const float* opool = part[0];
        float s = 0.f;
        #pragma unroll 8
        for (int c = 0; c < 256; c += 4) {
            float4 wv = *(const float4*)(wrow + c);
            s += opool[c] * wv.x + opool[c + 1] * wv.y
               + opool[c + 2] * wv.z + opool[c + 3] * wv.w;
        }
        float m = smsum;
        float val = (s + bo[t] * m) / (m + 1e-10f);
        U16 vH, vL; split_hl(val, vH, vL);
        sent_hi[(size_t)b * 256 + t] = vH;
        sent_lo[(size_t)b * 256 + t] = vL;
    }
    if (t == 0) smask[b] = (smsum > 0.f) ? 1.f : 0.f;
}

// ---- levels 2/3: L in {16, 8}; unchanged (passes, ~30 us total) ----
template <int L>
__global__ __launch_bounds__(256) void mha_small(
    const U16* __restrict__ xh, const U16* __restrict__ xl,
    const float* __restrict__ mk,
    const U16* __restrict__ Wqh, const U16* __restrict__ Wql,
    const float* __restrict__ bqkv,
    const U16* __restrict__ Woh, const U16* __restrict__ Wol,
    const float* __restrict__ bo,
    float* __restrict__ out_f32, U16* __restrict__ out_hi, U16* __restrict__ out_lo,
    float* __restrict__ outmask)
{
    __shared__ __align__(16) U16 xs_h[16*256], xs_l[16*256];
    __shared__ __align__(16) U16 Qh_[16*256], Ql_[16*256];
    __shared__ __align__(16) U16 Kh_[16*256], Kl_[16*256];
    __shared__ __align__(16) U16 Vh_[256*32], Vl_[256*32];
    __shared__ __align__(16) U16 Ph_[4][16*32], Pl_[4][16*32];
    __shared__ __align__(16) U16 Oh_[16*256], Ol_[16*256];
    __shared__ float msk[16];
    __shared__ float smsum;

    const int t = threadIdx.x;
    const int w = t >> 6, l = t & 63, l15 = l & 15, lhi = l >> 4;
    const int b = blockIdx.x;

    if (t < 16) msk[t] = (t < L) ? mk[b*L + t] : 0.f;

    #pragma unroll
    for (int i = 0; i < 2; ++i) {
        int c = i*256 + t;
        int row = c >> 5, c8 = c & 31;
        u32x4 hv = u32x4{0,0,0,0}, lv = u32x4{0,0,0,0};
        if (row < L) {
            hv = *(const u32x4*)(xh + ((size_t)b*L + row)*256 + c8*8);
            lv = *(const u32x4*)(xl + ((size_t)b*L + row)*256 + c8*8);
        }
        int slot = c8 ^ (row & 7);
        *(u32x4*)(xs_h + row*256 + slot*8) = hv;
        *(u32x4*)(xs_l + row*256 + slot*8) = lv;
    }
    #pragma unroll
    for (int i = 0; i < 4; ++i) {
        int c = i*256 + t;
        *(u32x4*)(Vh_ + c*8) = u32x4{0,0,0,0};
        *(u32x4*)(Vl_ + c*8) = u32x4{0,0,0,0};
    }
    *(u32x4*)(&Ph_[0][0] + t*8) = u32x4{0,0,0,0};
    *(u32x4*)(&Pl_[0][0] + t*8) = u32x4{0,0,0,0};
    __syncthreads();
    if (t == 0) { float s = 0.f; for (int i = 0; i < 16; ++i) s += msk[i]; smsum = s; }

    {
        f32x4 acc[12];
        #pragma unroll
        for (int i = 0; i < 12; ++i) acc[i] = f32x4{0.f,0.f,0.f,0.f};
        #pragma unroll 2
        for (int k0 = 0; k0 < 256; k0 += 32) {
            u32x4 ah = fragp<256,7>(xs_h, l15, k0, lhi);
            u32x4 al = fragp<256,7>(xs_l, l15, k0, lhi);
            #pragma unroll
            for (int j = 0; j < 12; ++j) {
                int u = w*12 + j;
                u32x4 wh = *(const u32x4*)(Wqh + (size_t)(u*16 + l15)*256 + k0 + lhi*8);
                u32x4 wl = *(const u32x4*)(Wql + (size_t)(u*16 + l15)*256 + k0 + lhi*8);
                acc[j] = MFMA(ah, wh, acc[j]);
                acc[j] = MFMA(ah, wl, acc[j]);
                acc[j] = MFMA(al, wh, acc[j]);
            }
        }
        #pragma unroll
        for (int j = 0; j < 12; ++j) {
            int u = w*12 + j;
            int mat = u >> 4, cg = u & 15;
            float bias = bqkv[u*16 + l15];
            if (mat < 2) {
                U16* dh = (mat == 0) ? Qh_ : Kh_;
                U16* dl = (mat == 0) ? Ql_ : Kl_;
                #pragma unroll
                for (int r = 0; r < 4; ++r) {
                    U16 vH, vL; split_hl(acc[j][r] + bias, vH, vL);
                    put16<256,7>(dh, lhi*4 + r, cg*16 + l15, vH);
                    put16<256,7>(dl, lhi*4 + r, cg*16 + l15, vL);
                }
            } else {
                U16 h4[4], l4[4];
                #pragma unroll
                for (int r = 0; r < 4; ++r) split_hl(acc[j][r] + bias, h4[r], l4[r]);
                put64<32,3>(Vh_, cg*16 + l15, lhi*4, h4[0],h4[1],h4[2],h4[3]);
                put64<32,3>(Vl_, cg*16 + l15, lhi*4, l4[0],l4[1],l4[2],l4[3]);
            }
        }
    }
    __syncthreads();

    {
        const int h = w;
        f32x4 sa = f32x4{0.f,0.f,0.f,0.f};
        #pragma unroll
        for (int k0 = 0; k0 < 64; k0 += 32) {
            u32x4 qh = fragp<256,7>(Qh_, l15, h*64 + k0, lhi);
            u32x4 ql = fragp<256,7>(Ql_, l15, h*64 + k0, lhi);
            u32x4 kh = fragp<256,7>(Kh_, l15, h*64 + k0, lhi);
            u32x4 kl = fragp<256,7>(Kl_, l15, h*64 + k0, lhi);
            sa = MFMA(qh, kh, sa);
            sa = MFMA(qh, kl, sa);
            sa = MFMA(ql, kh, sa);
        }
        float sc[4];
        float mterm = (1.0f - msk[l15]) * -1e9f;
        #pragma unroll
        for (int r = 0; r < 4; ++r) sc[r] = sa[r] * 0.125f + mterm;
        #pragma unroll
        for (int r = 0; r < 4; ++r) {
            float m = sc[r];
            #pragma unroll
            for (int off = 1; off < 16; off <<= 1) m = fmaxf(m, __shfl_xor(m, off));
            float e = expf(sc[r] - m);
            float s = e;
            #pragma unroll
            for (int off = 1; off < 16; off <<= 1) s += __shfl_xor(s, off);
            sc[r] = e / s;
        }
        #pragma unroll
        for (int r = 0; r < 4; ++r) {
            U16 vH, vL; split_hl(sc[r], vH, vL);
            put16<32,3>(&Ph_[h][0], lhi*4 + r, l15, vH);
            put16<32,3>(&Pl_[h][0], lhi*4 + r, l15, vL);
        }
        f32x4 pa[4];
        #pragma unroll
        for (int i = 0; i < 4; ++i) pa[i] = f32x4{0.f,0.f,0.f,0.f};
        {
            u32x4 ph = fragp<32,3>(&Ph_[h][0], l15, 0, lhi);
            u32x4 pl = fragp<32,3>(&Pl_[h][0], l15, 0, lhi);
            #pragma unroll
            for (int ntl = 0; ntl < 4; ++ntl) {
                u32x4 vh = fragp<32,3>(Vh_, h*64 + ntl*16 + l15, 0, lhi);
                u32x4 vl = fragp<32,3>(Vl_, h*64 + ntl*16 + l15, 0, lhi);
                pa[ntl] = MFMA(ph, vh, pa[ntl]);
                pa[ntl] = MFMA(ph, vl, pa[ntl]);
                pa[ntl] = MFMA(pl, vh, pa[ntl]);
            }
        }
        #pragma unroll
        for (int ntl = 0; ntl < 4; ++ntl) {
            #pragma unroll
            for (int r = 0; r < 4; ++r) {
                U16 vH, vL; split_hl(pa[ntl][r], vH, vL);
                put16<256,7>(Oh_, lhi*4 + r, h*64 + ntl*16 + l15, vH);
                put16<256,7>(Ol_, lhi*4 + r, h*64 + ntl*16 + l15, vL);
            }
        }
    }
    __syncthreads();

    {
        f32x4 acc4[4];
        #pragma unroll
        for (int i = 0; i < 4; ++i) acc4[i] = f32x4{0.f,0.f,0.f,0.f};
        #pragma unroll 2
        for (int k0 = 0; k0 < 256; k0 += 32) {
            u32x4 oh = fragp<256,7>(Oh_, l15, k0, lhi);
            u32x4 ol = fragp<256,7>(Ol_, l15, k0, lhi);
            #pragma unroll
            for (int j = 0; j < 4; ++j) {
                int oc = w*64 + j*16 + l15;
                u32x4 wh = *(const u32x4*)(Woh + (size_t)oc*256 + k0 + lhi*8);
                u32x4 wl = *(const u32x4*)(Wol + (size_t)oc*256 + k0 + lhi*8);
                acc4[j] = MFMA(oh, wh, acc4[j]);
                acc4[j] = MFMA(oh, wl, acc4[j]);
                acc4[j] = MFMA(ol, wh, acc4[j]);
            }
        }
        float msum = smsum;
        #pragma unroll
        for (int j = 0; j < 4; ++j) {
            float s = 0.f;
            #pragma unroll
            for (int r = 0; r < 4; ++r) s += msk[lhi*4 + r] * acc4[j][r];
            s += __shfl_xor(s, 16);
            s += __shfl_xor(s, 32);
            if (lhi == 0) {
                int col = w*64 + j*16 + l15;
                float val = (s + bo[col] * msum) / (msum + 1e-10f);
                if (out_f32) out_f32[(size_t)b*256 + col] = val;
                if (out_hi) {
                    U16 vH, vL; split_hl(val, vH, vL);
                    out_hi[(size_t)b*256 + col] = vH;
                    out_lo[(size_t)b*256 + col] = vL;
                }
            }
        }
    }
    if (t == 0 && outmask) outmask[b] = (smsum > 0.f) ? 1.f : 0.f;
}

extern "C" void kernel_launch(void* const* d_in, const int* in_sizes, int n_in,
                              void* d_out, int out_size, void* d_ws, size_t ws_size,
                              hipStream_t stream) {
    (void)in_sizes; (void)n_in; (void)out_size; (void)ws_size;
    const float* we  = (const float*)d_in[0];
    const int*   am  = (const int*)d_in[1];
    const float* wW  = (const float*)d_in[2];
    const float* wb  = (const float*)d_in[3];
    const float* wO  = (const float*)d_in[4];
    const float* wob = (const float*)d_in[5];
    const float* sW  = (const float*)d_in[6];
    const float* sb  = (const float*)d_in[7];
    const float* sO  = (const float*)d_in[8];
    const float* sob = (const float*)d_in[9];
    const float* cW  = (const float*)d_in[10];
    const float* cb  = (const float*)d_in[11];
    const float* cO  = (const float*)d_in[12];
    const float* cob = (const float*)d_in[13];

    U16* p = (U16*)d_ws;
    U16* sent_hi = p; p += 2048*256;
    U16* sent_lo = p; p += 2048*256;
    U16* sect_hi = p; p += 128*256;
    U16* sect_lo = p; p += 128*256;
    U16* w1qh = p; p += 768*256;  U16* w1ql = p; p += 768*256;
    U16* w1oh = p; p += 256*256;  U16* w1ol = p; p += 256*256;
    U16* w2qh = p; p += 768*256;  U16* w2ql = p; p += 768*256;
    U16* w2oh = p; p += 256*256;  U16* w2ol = p; p += 256*256;
    U16* w3qh = p; p += 768*256;  U16* w3ql = p; p += 768*256;
    U16* w3oh = p; p += 256*256;  U16* w3ol = p; p += 256*256;
    float* smaskb = (float*)p;
    float* cmaskb = smaskb + 2048;

    convert_w3<<<3 * 768, 256, 0, stream>>>(
        wW, wO, w1qh, w1ql, w1oh, w1ol,
        sW, sO, w2qh, w2ql, w2oh, w2ol,
        cW, cO, w3qh, w3ql, w3oh, w3ol);
    word_mfma<<<2048, 256, 0, stream>>>(we, am, w1qh, w1ql, wb, wO, wob,
                                        sent_hi, sent_lo, smaskb);
    mha_small<16><<<128, 256, 0, stream>>>(sent_hi, sent_lo, smaskb,
                                           w2qh, w2ql, sb, w2oh, w2ol, sob,
                                           nullptr, sect_hi, sect_lo, cmaskb);
    mha_small<8><<<16, 256, 0, stream>>>(sect_hi, sect_lo, cmaskb,
                                         w3qh, w3ql, cb, w3oh, w3ol, cob,
                                         (float*)d_out, nullptr, nullptr, nullptr);
}